// Round 4
// baseline (1077.436 us; speedup 1.0000x reference)
//
#include <hip/hip_runtime.h>
#include <hip/hip_bf16.h>
#include <stdint.h>
#include <stdio.h>

// Problem dims (fixed by the reference)
#define T_SEQ  2048
#define BATCH  2
#define NROWS  4096   // B*T
#define EMBED  512
#define HIDDEN 1024
#define VOCAB  32000
#define NCHUNK 128
#define CHLEN  16     // T_SEQ / NCHUNK

typedef __bf16 bf16x8 __attribute__((ext_vector_type(8)));
typedef float  f32x4  __attribute__((ext_vector_type(4)));

__device__ __forceinline__ float b2f(unsigned short h) {
  union { unsigned int u; float f; } v; v.u = ((unsigned int)h) << 16; return v.f;
}
__device__ __forceinline__ unsigned short f2b(float f) {
  union { float f; unsigned int u; } v; v.f = f;
  unsigned int u = v.u;
  u += 0x7fffu + ((u >> 16) & 1u);   // round-to-nearest-even
  return (unsigned short)(u >> 16);
}

// -------- fused gather + chunk-sum: emb = bf16(E[tok]); csum[bc] = Σ chunk --------
__global__ void gather_sum_kernel(const int* __restrict__ tokens,
                                  const float* __restrict__ E,
                                  unsigned short* __restrict__ emb,
                                  float* __restrict__ csum) {
  const int bc = blockIdx.x;               // b*NCHUNK + c  (256 blocks)
  const int d  = threadIdx.x;              // 0..511
  __shared__ int tok[CHLEN];
  if (d < CHLEN) tok[d] = tokens[bc * CHLEN + d];
  __syncthreads();
  float s = 0.f;
  unsigned short* eo = emb + ((size_t)bc * CHLEN) * EMBED + d;
  #pragma unroll 4
  for (int i = 0; i < CHLEN; ++i) {
    const float v = E[(size_t)tok[i] * EMBED + d];
    const unsigned short h = f2b(v);
    eo[(size_t)i * EMBED] = h;
    s += b2f(h);                           // bf16-rounded accumulation (matches emit)
  }
  csum[(size_t)bc * EMBED + d] = s;
}

// -------- exclusive scan over chunks: LDS column scan (no serial HBM trips) -----
// grid (BATCH, EMBED/128), 128 threads. Thread t owns dim d0+t across all chunks.
__global__ void scan_excl_kernel(float* __restrict__ csum) {
  const int b  = blockIdx.x;
  const int d0 = blockIdx.y << 7;
  const int t  = threadIdx.x;
  __shared__ float s[NCHUNK][128];         // 64 KB
  for (int c = 0; c < NCHUNK; ++c)         // 128 independent coalesced loads
    s[c][t] = csum[((size_t)b * NCHUNK + c) * EMBED + d0 + t];
  float run = 0.f;                         // column-private: no sync needed
  for (int c = 0; c < NCHUNK; ++c) {
    const float v = s[c][t];
    csum[((size_t)b * NCHUNK + c) * EMBED + d0 + t] = run;
    run += v;
  }
}

__global__ void scan_emit_kernel(const unsigned short* __restrict__ emb,
                                 const float* __restrict__ csum,
                                 unsigned short* __restrict__ hist) {
  const int bc = blockIdx.x;                 // b*NCHUNK + c  (256 blocks)
  const int c  = bc & (NCHUNK - 1);
  const int d  = threadIdx.x;
  const unsigned short* e = emb  + ((size_t)bc * CHLEN) * EMBED + d;
  unsigned short*       h = hist + ((size_t)bc * CHLEN) * EMBED + d;
  float sum = csum[(size_t)bc * EMBED + d];  // exclusive prefix
  #pragma unroll 8
  for (int i = 0; i < CHLEN; ++i) {
    const int t = c * CHLEN + i;
    h[(size_t)i * EMBED] = (t == 0) ? e[0] : f2b(sum / (float)t);
    sum += b2f(e[(size_t)i * EMBED]);
  }
}

// -------- single-launch transpose+cast for all 4 weights, 64x64 f32 tiles --------
__global__ __launch_bounds__(256) void transpose_all_kernel(
    const float* __restrict__ Wc, const float* __restrict__ Wh,
    const float* __restrict__ Wm, const float* __restrict__ Wo,
    unsigned short* __restrict__ WcT, unsigned short* __restrict__ WhT,
    unsigned short* __restrict__ WmT, unsigned short* __restrict__ WoT) {
  const int id = blockIdx.x;
  const float* in; unsigned short* out; int R, C, t;
  if (id < 128)      { in = Wc; out = WcT; R = 512;  C = 1024;  t = id; }
  else if (id < 256) { in = Wh; out = WhT; R = 512;  C = 1024;  t = id - 128; }
  else if (id < 768) { in = Wm; out = WmT; R = 2048; C = 1024;  t = id - 256; }
  else               { in = Wo; out = WoT; R = 1024; C = 32000; t = id - 768; }
  const int tilesX = C >> 6;
  const int r0 = (t / tilesX) << 6, c0 = (t % tilesX) << 6;

  __shared__ float tile[64][65];
  const int tid = threadIdx.x;
  #pragma unroll
  for (int p = 0; p < 4; ++p) {
    const int u = tid + p * 256;
    const int row = u >> 4, cq = (u & 15) << 2;
    const float4 v = *(const float4*)&in[(size_t)(r0 + row) * C + c0 + cq];
    tile[row][cq + 0] = v.x; tile[row][cq + 1] = v.y;
    tile[row][cq + 2] = v.z; tile[row][cq + 3] = v.w;
  }
  __syncthreads();
  #pragma unroll
  for (int p = 0; p < 4; ++p) {
    const int u = tid + p * 256;
    const int oc = u >> 4, org = (u & 15) << 2;
    ushort4 o;
    o.x = f2b(tile[org + 0][oc]); o.y = f2b(tile[org + 1][oc]);
    o.z = f2b(tile[org + 2][oc]); o.w = f2b(tile[org + 3][oc]);
    *(ushort4*)&out[(size_t)(c0 + oc) * R + r0 + org] = o;
  }
}

__device__ __forceinline__ void async16(unsigned short* lds, const unsigned short* g) {
  __builtin_amdgcn_global_load_lds(
      (const __attribute__((address_space(1))) void*)g,
      (__attribute__((address_space(3))) void*)lds, 16, 0, 0);
}

// ---------------- 128x128 MFMA GEMM (encode / merge) ----------------
// MODE 0: relu -> bf16 ; MODE 1: relu -> f32
#define BM 128
#define BN 128
#define BK 32

template<int MODE>
__global__ __launch_bounds__(256) void gemm_bt_kernel(
    const unsigned short* __restrict__ A,
    const unsigned short* __restrict__ BT,
    const float* __restrict__ bias,
    void* __restrict__ out, int M, int N, int K, int ldOut, int colOff,
    const unsigned short* __restrict__ A2,
    const unsigned short* __restrict__ BT2,
    const float* __restrict__ bias2, int colOff2) {
  __shared__ unsigned short As[BM * BK];
  __shared__ unsigned short Bs[BN * BK];

  const unsigned short* Ap = A;
  const unsigned short* Bp = BT;
  const float*          bp = bias;
  int                   co = colOff;
  if (blockIdx.z) { Ap = A2; Bp = BT2; bp = bias2; co = colOff2; }

  int wg = blockIdx.x;
  {
    const int nwg = gridDim.x;
    const int xcd = wg & 7, loc = wg >> 3;
    const int q = nwg >> 3, r = nwg & 7;
    wg = (xcd < r ? xcd * (q + 1) : r * (q + 1) + (xcd - r) * q) + loc;
  }
  const int nmb = M / BM;
  const int mb  = wg % nmb;
  const int nb  = wg / nmb;
  const int m0  = mb * BM;
  const int n0  = nb * BN;

  const int tid  = threadIdx.x;
  const int wave = tid >> 6;
  const int lane = tid & 63;
  const int wm = (wave & 1) * 64;
  const int wn = (wave >> 1) * 64;

  const int srow = (wave << 5) + (lane >> 2);
  const int scol = (lane & 3) << 3;
  const unsigned short* aSrc = Ap + (size_t)(m0 + srow) * K + scol;
  const unsigned short* bSrc = Bp + (size_t)(n0 + srow) * K + scol;
  unsigned short* aDst = As + (wave << 5) * BK;
  unsigned short* bDst = Bs + (wave << 5) * BK;

  f32x4 acc[4][4];
  #pragma unroll
  for (int i = 0; i < 4; ++i)
    #pragma unroll
    for (int j = 0; j < 4; ++j)
      acc[i][j] = (f32x4){0.f, 0.f, 0.f, 0.f};

  const int q = lane >> 4;
  const int r = lane & 15;

  for (int k0 = 0; k0 < K; k0 += BK) {
    __syncthreads();
    async16(aDst,           aSrc);
    async16(aDst + 16 * BK, aSrc + 16 * (size_t)K);
    async16(bDst,           bSrc);
    async16(bDst + 16 * BK, bSrc + 16 * (size_t)K);
    aSrc += BK; bSrc += BK;
    __syncthreads();

    bf16x8 af[4], bfr[4];
    #pragma unroll
    for (int mi = 0; mi < 4; ++mi)
      af[mi] = *(const bf16x8*)&As[(wm + mi * 16 + r) * BK + (q << 3)];
    #pragma unroll
    for (int ni = 0; ni < 4; ++ni)
      bfr[ni] = *(const bf16x8*)&Bs[(wn + ni * 16 + r) * BK + (q << 3)];
    #pragma unroll
    for (int mi = 0; mi < 4; ++mi)
      #pragma unroll
      for (int ni = 0; ni < 4; ++ni)
        acc[mi][ni] = __builtin_amdgcn_mfma_f32_16x16x32_bf16(
            af[mi], bfr[ni], acc[mi][ni], 0, 0, 0);
  }

  #pragma unroll
  for (int ni = 0; ni < 4; ++ni) {
    const int col = n0 + wn + ni * 16 + r;
    const float bv = bp[col];
    #pragma unroll
    for (int mi = 0; mi < 4; ++mi) {
      #pragma unroll
      for (int e = 0; e < 4; ++e) {
        const int row = m0 + wm + mi * 16 + (q << 2) + e;
        float v = fmaxf(acc[mi][ni][e] + bv, 0.f);
        const size_t idx = (size_t)row * ldOut + co + col;
        if (MODE == 0) ((unsigned short*)out)[idx] = f2b(v);
        else           ((float*)out)[idx] = v;
      }
    }
  }
}

// ============ 128x128 / BK=32 / 4-wave pipelined GEMM (logits) ============
// Occupancy-first redesign: acc 64 f32/thread, 32 KB LDS -> target 4 blocks/CU
// (16 waves/CU) so barrier/lgkm/vmcnt stalls are filled by co-resident blocks.
// Keeps: T2 XOR swizzle (2-bit slot, linear gload_lds dest + inverse-swizzled
// global source), counted vmcnt(4) (never 0 in steady state), T5 setprio,
// LDS-bounced full-line epilogue, m-fastest + bijective XCD chunk swizzle.
//
// Per K-tile (32): p1 {8 ds_read_b128; 8 MFMA (mi0-1); BAR}  -> tile regions dead
//                  p2 {stage 4 gload_lds for u+2; 8 MFMA (mi2-3); vmcnt(4); BAR}

#define BAR() do {                            \
    asm volatile("" ::: "memory");            \
    __builtin_amdgcn_sched_barrier(0);        \
    __builtin_amdgcn_s_barrier();             \
    __builtin_amdgcn_sched_barrier(0);        \
    asm volatile("" ::: "memory");            \
  } while (0)

__global__ __launch_bounds__(256, 4) void gemm_out_kernel(
    const unsigned short* __restrict__ A,
    const unsigned short* __restrict__ BT,
    const float* __restrict__ bias,
    float* __restrict__ out, int M, int N, int K, int ldOut) {
  // [buf][A=0/B=1][128 rows x 32 k bf16] = 8 KB each, 32 KB total
  __shared__ unsigned short lds[2][2][4096];

  int wg = blockIdx.x;
  {
    const int nwg = gridDim.x;
    const int xcd = wg & 7, loc = wg >> 3;
    const int q8 = nwg >> 3, r8 = nwg & 7;
    wg = (xcd < r8 ? xcd * (q8 + 1) : r8 * (q8 + 1) + (xcd - r8) * q8) + loc;
  }
  const int nmb = M >> 7;
  const int mb = wg % nmb, nb = wg / nmb;   // m-fastest: 32 blocks share B-panel
  const int m0 = mb << 7, n0 = nb << 7;

  const int tid  = threadIdx.x;
  const int wave = tid >> 6, lane = tid & 63;
  const int wm = (wave & 1) << 6, wn = (wave >> 1) << 6;  // 2x2 waves, 64x64 each
  const int q = lane >> 4, r = lane & 15;

  // staging: one async16 = 1 KB = 16 rows of 64 B. Each wave: rows wave*32..+31
  // (2 instrs). Physical 16B slot = lane&3; inverse swizzle on SOURCE col.
  const int srow = (wave << 5) + (lane >> 2);
  const int scol = ((lane & 3) ^ ((lane >> 2) & 3)) << 3;
  const unsigned short* aB = A  + (size_t)(m0 + srow) * K + scol;
  const unsigned short* bB = BT + (size_t)(n0 + srow) * K + scol;

  const int NTt = K >> 5;   // K-tiles of 32

  auto stage = [&](int matB, int tb, int kt) {
    unsigned short* d = &lds[tb][matB][wave << 10];
    const unsigned short* s = (matB ? bB : aB) + ((size_t)kt << 5);
    async16(d, s);
    async16(d + 512, s + ((size_t)K << 4));   // +16 rows
  };

  // swizzled reads: row = 64 B = 4 slots of 16 B; physical slot = q ^ (row&3)
  auto ldA = [&](int tb, int mi) {
    const int row = wm + mi * 16 + r;
    return *(const bf16x8*)&lds[tb][0][(row << 5) + ((q ^ (r & 3)) << 3)];
  };
  auto ldB = [&](int tb, int nj) {
    const int row = wn + nj * 16 + r;
    return *(const bf16x8*)&lds[tb][1][(row << 5) + ((q ^ (r & 3)) << 3)];
  };

  f32x4 acc[4][4];
  #pragma unroll
  for (int i = 0; i < 4; ++i)
    #pragma unroll
    for (int j = 0; j < 4; ++j)
      acc[i][j] = (f32x4){0.f, 0.f, 0.f, 0.f};

  // prologue: tiles 0,1 staged (8 loads); vmcnt(4) retires tile 0 only.
  stage(0, 0, 0); stage(1, 0, 0);
  if (NTt > 1) {
    stage(0, 1, 1); stage(1, 1, 1);
    asm volatile("s_waitcnt vmcnt(4)" ::: "memory");
  } else {
    asm volatile("s_waitcnt vmcnt(0)" ::: "memory");
  }
  BAR();

  for (int u = 0; u < NTt; ++u) {
    const int bu = u & 1;
    bf16x8 af[4], bf[4];
    // ---- p1: all frag reads, MFMA mi0-1 ----
    #pragma unroll
    for (int mi = 0; mi < 4; ++mi) af[mi] = ldA(bu, mi);
    #pragma unroll
    for (int nj = 0; nj < 4; ++nj) bf[nj] = ldB(bu, nj);
    __builtin_amdgcn_s_setprio(1);
    #pragma unroll
    for (int mi = 0; mi < 2; ++mi)
      #pragma unroll
      for (int nj = 0; nj < 4; ++nj)
        acc[mi][nj] = __builtin_amdgcn_mfma_f32_16x16x32_bf16(
            af[mi], bf[nj], acc[mi][nj], 0, 0, 0);
    __builtin_amdgcn_s_setprio(0);
    BAR();                                   // all waves done reading buf bu
    // ---- p2: stage u+2 into dead buf, MFMA mi2-3, counted vmcnt ----
    if (u + 2 < NTt) { stage(0, bu, u + 2); stage(1, bu, u + 2); }
    __builtin_amdgcn_s_setprio(1);
    #pragma unroll
    for (int mi = 2; mi < 4; ++mi)
      #pragma unroll
      for (int nj = 0; nj < 4; ++nj)
        acc[mi][nj] = __builtin_amdgcn_mfma_f32_16x16x32_bf16(
            af[mi], bf[nj], acc[mi][nj], 0, 0, 0);
    __builtin_amdgcn_s_setprio(0);
    if (u + 2 < NTt) asm volatile("s_waitcnt vmcnt(4)" ::: "memory");
    else             asm volatile("s_waitcnt vmcnt(0)" ::: "memory");
    BAR();
  }

  // ---- LDS-coalesced epilogue: (x+bias)*0.1, full-line f32x4 stores ----
  // 2 passes of 64 rows; scratch 64x128 f32 = 32 KB (reuses lds).
  // Deposit col ^= q<<4 (q=(row>>2)&3) -> 2-way max; read-back undoes it.
  float* scratch = (float*)&lds[0][0][0];
  const int wmi = wave & 1;
  #pragma unroll
  for (int g = 0; g < 2; ++g) {
    if (wmi == g) {
      #pragma unroll
      for (int nj = 0; nj < 4; ++nj) {
        const int col = wn + nj * 16 + r;
        const float bv = bias[n0 + col];
        #pragma unroll
        for (int mi = 0; mi < 4; ++mi) {
          #pragma unroll
          for (int e = 0; e < 4; ++e) {
            const int row = mi * 16 + (q << 2) + e;   // 0..63  (row>>2)&3 == q
            scratch[row * 128 + (col ^ (q << 4))] = (acc[mi][nj][e] + bv) * 0.1f;
          }
        }
      }
    }
    __syncthreads();
    #pragma unroll
    for (int i = 0; i < 8; ++i) {
      const int row = (wave << 4) + (i << 1) + (lane >> 5);
      const int cb  = (lane & 31) << 2;
      const f32x4 v4 =
          *(const f32x4*)&scratch[row * 128 + (cb ^ (((row >> 2) & 3) << 4))];
      *(f32x4*)&out[(size_t)(m0 + (g << 6) + row) * ldOut + n0 + cb] = v4;
    }
    __syncthreads();
  }
}

// ---------------- LayerNorm over last dim (1024), f32 in -> bf16 out ----------------
__global__ void ln_kernel(const float* __restrict__ merged,
                          const float* __restrict__ lnw,
                          const float* __restrict__ lnb,
                          unsigned short* __restrict__ normed) {
  const int row = blockIdx.x;
  const float4 v = ((const float4*)(merged + (size_t)row * HIDDEN))[threadIdx.x];
  float s  = v.x + v.y + v.z + v.w;
  float ss = v.x * v.x + v.y * v.y + v.z * v.z + v.w * v.w;
  #pragma unroll
  for (int off = 32; off > 0; off >>= 1) {
    s  += __shfl_down(s, off, 64);
    ss += __shfl_down(ss, off, 64);
  }
  __shared__ float red[8];
  const int wvi = threadIdx.x >> 6;
  if ((threadIdx.x & 63) == 0) { red[wvi] = s; red[4 + wvi] = ss; }
  __syncthreads();
  s  = red[0] + red[1] + red[2] + red[3];
  ss = red[4] + red[5] + red[6] + red[7];
  const float mu  = s * (1.0f / HIDDEN);
  const float var = ss * (1.0f / HIDDEN) - mu * mu;
  const float rs  = rsqrtf(var + 1e-5f);
  const float4 w4 = ((const float4*)lnw)[threadIdx.x];
  const float4 b4 = ((const float4*)lnb)[threadIdx.x];
  ushort4 o;
  o.x = f2b((v.x - mu) * rs * w4.x + b4.x);
  o.y = f2b((v.y - mu) * rs * w4.y + b4.y);
  o.z = f2b((v.z - mu) * rs * w4.z + b4.z);
  o.w = f2b((v.w - mu) * rs * w4.w + b4.w);
  ((ushort4*)(normed + (size_t)row * HIDDEN))[threadIdx.x] = o;
}

extern "C" void kernel_launch(void* const* d_in, const int* in_sizes, int n_in,
                              void* d_out, int out_size, void* d_ws, size_t ws_size,
                              hipStream_t stream) {
  const int*   tokens = (const int*)d_in[0];
  const float* E      = (const float*)d_in[1];
  const float* Wc     = (const float*)d_in[2];
  const float* bc     = (const float*)d_in[3];
  const float* Wh     = (const float*)d_in[4];
  const float* bh     = (const float*)d_in[5];
  const float* Wm     = (const float*)d_in[6];
  const float* bm     = (const float*)d_in[7];
  const float* Wo     = (const float*)d_in[8];
  const float* bo     = (const float*)d_in[9];
  const float* lnw    = (const float*)d_in[10];
  const float* lnb    = (const float*)d_in[11];

  char* p = (char*)d_ws;
  unsigned short* WcT  = (unsigned short*)p; p += (size_t)HIDDEN * EMBED * 2;
  unsigned short* WhT  = (unsigned short*)p; p += (size_t)HIDDEN * EMBED * 2;
  unsigned short* WmT  = (unsigned short*)p; p += (size_t)HIDDEN * (2 * HIDDEN) * 2;
  unsigned short* WoT  = (unsigned short*)p; p += (size_t)VOCAB * HIDDEN * 2;
  unsigned short* emb  = (unsigned short*)p; p += (size_t)NROWS * EMBED * 2;
  unsigned short* hist = (unsigned short*)p; p += (size_t)NROWS * EMBED * 2;
  unsigned short* cat  = (unsigned short*)p; p += (size_t)NROWS * (2 * HIDDEN) * 2;
  float*          mrg  = (float*)p;          p += (size_t)NROWS * HIDDEN * 4;
  unsigned short* nrm  = (unsigned short*)p; p += (size_t)NROWS * HIDDEN * 2;
  float*          csum = (float*)p;          p += (size_t)BATCH * NCHUNK * EMBED * 4;
  if ((size_t)(p - (char*)d_ws) > ws_size)
    fprintf(stderr, "WS TOO SMALL: need %zu have %zu\n", (size_t)(p - (char*)d_ws), ws_size);

  // all 4 weight transposes in one launch
  transpose_all_kernel<<<8768, 256, 0, stream>>>(Wc, Wh, Wm, Wo, WcT, WhT, WmT, WoT);

  gather_sum_kernel<<<BATCH * NCHUNK, EMBED, 0, stream>>>(tokens, E, emb, csum);
  scan_excl_kernel<<<dim3(BATCH, EMBED / 128), 128, 0, stream>>>(csum);
  scan_emit_kernel<<<BATCH * NCHUNK, EMBED, 0, stream>>>(emb, csum, hist);

  const int nwgEnc = (NROWS / BM) * (HIDDEN / BN);   // 256 tiles per slice

  // cur_enc / hist_enc fused into one launch (z=2) -> concatenated [4096, 2048] bf16
  gemm_bt_kernel<0><<<dim3(nwgEnc, 1, 2), 256, 0, stream>>>(
      emb, WcT, bc, cat, NROWS, HIDDEN, EMBED, 2 * HIDDEN, 0,
      hist, WhT, bh, HIDDEN);
  // merged = relu(cat @ Wm + bm), kept f32 for LN accuracy
  gemm_bt_kernel<1><<<dim3(nwgEnc, 1, 1), 256, 0, stream>>>(
      cat, WmT, bm, mrg, NROWS, HIDDEN, 2 * HIDDEN, HIDDEN, 0,
      nullptr, nullptr, nullptr, 0);
  ln_kernel<<<NROWS, 256, 0, stream>>>(mrg, lnw, lnb, nrm);

  // logits = (normed @ Wo + bo) * 0.1 -> d_out f32, occupancy-first 128^2 kernel
  const int nwgOut = (NROWS / 128) * (VOCAB / 128);  // 32 * 250 = 8000
  gemm_out_kernel<<<dim3(nwgOut), 256, 0, stream>>>(
      nrm, WoT, bo, (float*)d_out, NROWS, VOCAB, HIDDEN, VOCAB);
}

// Round 5
// 992.497 us; speedup vs baseline: 1.0856x; 1.0856x over previous
//
#include <hip/hip_runtime.h>
#include <hip/hip_bf16.h>
#include <stdint.h>
#include <stdio.h>

// Problem dims (fixed by the reference)
#define T_SEQ  2048
#define BATCH  2
#define NROWS  4096   // B*T
#define EMBED  512
#define HIDDEN 1024
#define VOCAB  32000
#define NCHUNK 128
#define CHLEN  16     // T_SEQ / NCHUNK

typedef __bf16 bf16x8 __attribute__((ext_vector_type(8)));
typedef float  f32x4  __attribute__((ext_vector_type(4)));

__device__ __forceinline__ float b2f(unsigned short h) {
  union { unsigned int u; float f; } v; v.u = ((unsigned int)h) << 16; return v.f;
}
__device__ __forceinline__ unsigned short f2b(float f) {
  union { float f; unsigned int u; } v; v.f = f;
  unsigned int u = v.u;
  u += 0x7fffu + ((u >> 16) & 1u);   // round-to-nearest-even
  return (unsigned short)(u >> 16);
}

// -------- fused gather + chunk-sum: emb = bf16(E[tok]); csum[bc] = Σ chunk --------
__global__ void gather_sum_kernel(const int* __restrict__ tokens,
                                  const float* __restrict__ E,
                                  unsigned short* __restrict__ emb,
                                  float* __restrict__ csum) {
  const int bc = blockIdx.x;               // b*NCHUNK + c  (256 blocks)
  const int d  = threadIdx.x;              // 0..511
  __shared__ int tok[CHLEN];
  if (d < CHLEN) tok[d] = tokens[bc * CHLEN + d];
  __syncthreads();
  float s = 0.f;
  unsigned short* eo = emb + ((size_t)bc * CHLEN) * EMBED + d;
  #pragma unroll 4
  for (int i = 0; i < CHLEN; ++i) {
    const float v = E[(size_t)tok[i] * EMBED + d];
    const unsigned short h = f2b(v);
    eo[(size_t)i * EMBED] = h;
    s += b2f(h);                           // bf16-rounded accumulation (matches emit)
  }
  csum[(size_t)bc * EMBED + d] = s;
}

// -------- exclusive scan over chunks: LDS column scan (no serial HBM trips) -----
__global__ void scan_excl_kernel(float* __restrict__ csum) {
  const int b  = blockIdx.x;
  const int d0 = blockIdx.y << 7;
  const int t  = threadIdx.x;
  __shared__ float s[NCHUNK][128];         // 64 KB
  for (int c = 0; c < NCHUNK; ++c)
    s[c][t] = csum[((size_t)b * NCHUNK + c) * EMBED + d0 + t];
  float run = 0.f;                         // column-private: no sync needed
  for (int c = 0; c < NCHUNK; ++c) {
    const float v = s[c][t];
    csum[((size_t)b * NCHUNK + c) * EMBED + d0 + t] = run;
    run += v;
  }
}

__global__ void scan_emit_kernel(const unsigned short* __restrict__ emb,
                                 const float* __restrict__ csum,
                                 unsigned short* __restrict__ hist) {
  const int bc = blockIdx.x;                 // b*NCHUNK + c  (256 blocks)
  const int c  = bc & (NCHUNK - 1);
  const int d  = threadIdx.x;
  const unsigned short* e = emb  + ((size_t)bc * CHLEN) * EMBED + d;
  unsigned short*       h = hist + ((size_t)bc * CHLEN) * EMBED + d;
  float sum = csum[(size_t)bc * EMBED + d];  // exclusive prefix
  #pragma unroll 8
  for (int i = 0; i < CHLEN; ++i) {
    const int t = c * CHLEN + i;
    h[(size_t)i * EMBED] = (t == 0) ? e[0] : f2b(sum / (float)t);
    sum += b2f(e[(size_t)i * EMBED]);
  }
}

// -------- single-launch transpose+cast for all 4 weights, 64x64 f32 tiles --------
__global__ __launch_bounds__(256) void transpose_all_kernel(
    const float* __restrict__ Wc, const float* __restrict__ Wh,
    const float* __restrict__ Wm, const float* __restrict__ Wo,
    unsigned short* __restrict__ WcT, unsigned short* __restrict__ WhT,
    unsigned short* __restrict__ WmT, unsigned short* __restrict__ WoT) {
  const int id = blockIdx.x;
  const float* in; unsigned short* out; int R, C, t;
  if (id < 128)      { in = Wc; out = WcT; R = 512;  C = 1024;  t = id; }
  else if (id < 256) { in = Wh; out = WhT; R = 512;  C = 1024;  t = id - 128; }
  else if (id < 768) { in = Wm; out = WmT; R = 2048; C = 1024;  t = id - 256; }
  else               { in = Wo; out = WoT; R = 1024; C = 32000; t = id - 768; }
  const int tilesX = C >> 6;
  const int r0 = (t / tilesX) << 6, c0 = (t % tilesX) << 6;

  __shared__ float tile[64][65];
  const int tid = threadIdx.x;
  #pragma unroll
  for (int p = 0; p < 4; ++p) {
    const int u = tid + p * 256;
    const int row = u >> 4, cq = (u & 15) << 2;
    const float4 v = *(const float4*)&in[(size_t)(r0 + row) * C + c0 + cq];
    tile[row][cq + 0] = v.x; tile[row][cq + 1] = v.y;
    tile[row][cq + 2] = v.z; tile[row][cq + 3] = v.w;
  }
  __syncthreads();
  #pragma unroll
  for (int p = 0; p < 4; ++p) {
    const int u = tid + p * 256;
    const int oc = u >> 4, org = (u & 15) << 2;
    ushort4 o;
    o.x = f2b(tile[org + 0][oc]); o.y = f2b(tile[org + 1][oc]);
    o.z = f2b(tile[org + 2][oc]); o.w = f2b(tile[org + 3][oc]);
    *(ushort4*)&out[(size_t)(c0 + oc) * R + r0 + org] = o;
  }
}

__device__ __forceinline__ void async16(unsigned short* lds, const unsigned short* g) {
  __builtin_amdgcn_global_load_lds(
      (const __attribute__((address_space(1))) void*)g,
      (__attribute__((address_space(3))) void*)lds, 16, 0, 0);
}

// ---------------- 128x128 MFMA GEMM (encode / merge) ----------------
// MODE 0: relu -> bf16 ; MODE 1: relu -> f32
#define BM 128
#define BN 128
#define BK 32

template<int MODE>
__global__ __launch_bounds__(256) void gemm_bt_kernel(
    const unsigned short* __restrict__ A,
    const unsigned short* __restrict__ BT,
    const float* __restrict__ bias,
    void* __restrict__ out, int M, int N, int K, int ldOut, int colOff,
    const unsigned short* __restrict__ A2,
    const unsigned short* __restrict__ BT2,
    const float* __restrict__ bias2, int colOff2) {
  __shared__ unsigned short As[BM * BK];
  __shared__ unsigned short Bs[BN * BK];

  const unsigned short* Ap = A;
  const unsigned short* Bp = BT;
  const float*          bp = bias;
  int                   co = colOff;
  if (blockIdx.z) { Ap = A2; Bp = BT2; bp = bias2; co = colOff2; }

  int wg = blockIdx.x;
  {
    const int nwg = gridDim.x;
    const int xcd = wg & 7, loc = wg >> 3;
    const int q = nwg >> 3, r = nwg & 7;
    wg = (xcd < r ? xcd * (q + 1) : r * (q + 1) + (xcd - r) * q) + loc;
  }
  const int nmb = M / BM;
  const int mb  = wg % nmb;
  const int nb  = wg / nmb;
  const int m0  = mb * BM;
  const int n0  = nb * BN;

  const int tid  = threadIdx.x;
  const int wave = tid >> 6;
  const int lane = tid & 63;
  const int wm = (wave & 1) * 64;
  const int wn = (wave >> 1) * 64;

  const int srow = (wave << 5) + (lane >> 2);
  const int scol = (lane & 3) << 3;
  const unsigned short* aSrc = Ap + (size_t)(m0 + srow) * K + scol;
  const unsigned short* bSrc = Bp + (size_t)(n0 + srow) * K + scol;
  unsigned short* aDst = As + (wave << 5) * BK;
  unsigned short* bDst = Bs + (wave << 5) * BK;

  f32x4 acc[4][4];
  #pragma unroll
  for (int i = 0; i < 4; ++i)
    #pragma unroll
    for (int j = 0; j < 4; ++j)
      acc[i][j] = (f32x4){0.f, 0.f, 0.f, 0.f};

  const int q = lane >> 4;
  const int r = lane & 15;

  for (int k0 = 0; k0 < K; k0 += BK) {
    __syncthreads();
    async16(aDst,           aSrc);
    async16(aDst + 16 * BK, aSrc + 16 * (size_t)K);
    async16(bDst,           bSrc);
    async16(bDst + 16 * BK, bSrc + 16 * (size_t)K);
    aSrc += BK; bSrc += BK;
    __syncthreads();

    bf16x8 af[4], bfr[4];
    #pragma unroll
    for (int mi = 0; mi < 4; ++mi)
      af[mi] = *(const bf16x8*)&As[(wm + mi * 16 + r) * BK + (q << 3)];
    #pragma unroll
    for (int ni = 0; ni < 4; ++ni)
      bfr[ni] = *(const bf16x8*)&Bs[(wn + ni * 16 + r) * BK + (q << 3)];
    #pragma unroll
    for (int mi = 0; mi < 4; ++mi)
      #pragma unroll
      for (int ni = 0; ni < 4; ++ni)
        acc[mi][ni] = __builtin_amdgcn_mfma_f32_16x16x32_bf16(
            af[mi], bfr[ni], acc[mi][ni], 0, 0, 0);
  }

  #pragma unroll
  for (int ni = 0; ni < 4; ++ni) {
    const int col = n0 + wn + ni * 16 + r;
    const float bv = bp[col];
    #pragma unroll
    for (int mi = 0; mi < 4; ++mi) {
      #pragma unroll
      for (int e = 0; e < 4; ++e) {
        const int row = m0 + wm + mi * 16 + (q << 2) + e;
        float v = fmaxf(acc[mi][ni][e] + bv, 0.f);
        const size_t idx = (size_t)row * ldOut + co + col;
        if (MODE == 0) ((unsigned short*)out)[idx] = f2b(v);
        else           ((float*)out)[idx] = v;
      }
    }
  }
}

// ============ 256x256 8-wave deep-pipelined GEMM (logits) ============
// Round-3 structure (proven: race-free, 0 bank conflicts, counted vmcnt(6))
// with ONE change: m201-style split-barrier phases — ds_read issue and MFMA
// are separated by a barrier, with explicit lgkmcnt(0)+sched_barrier(0)
// (rule #18) before the MFMA cluster. Staging schedule & lifetimes unchanged.

#define BAR() do {                            \
    asm volatile("" ::: "memory");            \
    __builtin_amdgcn_sched_barrier(0);        \
    __builtin_amdgcn_s_barrier();             \
    __builtin_amdgcn_sched_barrier(0);        \
    asm volatile("" ::: "memory");            \
  } while (0)

#define WAITL0() do {                                      \
    asm volatile("s_waitcnt lgkmcnt(0)" ::: "memory");     \
    __builtin_amdgcn_sched_barrier(0);                     \
  } while (0)

__global__ __launch_bounds__(512, 2) void gemm256_out_kernel(
    const unsigned short* __restrict__ A,
    const unsigned short* __restrict__ BT,
    const float* __restrict__ bias,
    float* __restrict__ out, int M, int N, int K, int ldOut) {
  // [buf][mat A=0/B=1][half][128 rows * 64 cols]
  __shared__ unsigned short lds[2][2][2][8192];

  int wg = blockIdx.x;
  {
    const int nwg = gridDim.x;
    const int xcd = wg & 7, loc = wg >> 3;
    const int q8 = nwg >> 3, r8 = nwg & 7;
    wg = (xcd < r8 ? xcd * (q8 + 1) : r8 * (q8 + 1) + (xcd - r8) * q8) + loc;
  }
  const int nmb = M >> 8;
  const int mb = wg % nmb, nb = wg / nmb;
  const int m0 = mb << 8, n0 = nb << 8;

  const int tid  = threadIdx.x;
  const int wave = tid >> 6, lane = tid & 63;
  const int wr = wave >> 2, wc = wave & 3;     // 2x4 wave grid; per-wave out 128x64
  const int q = lane >> 4, r = lane & 15, rr = lane & 7;

  const int srow = (wave << 4) + (lane >> 3);          // row within half
  const int scol = ((lane & 7) ^ (lane >> 3)) << 3;    // inverse-swizzled src col
  const unsigned short* aB = A  + (size_t)(m0 + srow) * K + scol;
  const unsigned short* bB = BT + (size_t)(n0 + srow) * K + scol;

  const int NTt = K >> 6;  // K-tiles of 64

  auto stage = [&](int matB, int h, int tb, int kt) {
    unsigned short* d = &lds[tb][matB][h][wave << 10];
    const unsigned short* s =
        (matB ? bB : aB) + (size_t)h * 128 * K + ((size_t)kt << 6);
    async16(d, s);
    async16(d + 512, s + ((size_t)K << 3));
  };

  auto ldA = [&](int tb, int mi, int ks) {
    return *(const bf16x8*)&lds[tb][0][wr]
        [(mi * 16 + r) * 64 + ((((ks << 2) | q) ^ rr) << 3)];
  };
  auto ldB = [&](int tb, int ni, int ks) {
    return *(const bf16x8*)&lds[tb][1][wc >> 1]
        [(((wc & 1) << 6) + ni * 16 + r) * 64 + ((((ks << 2) | q) ^ rr) << 3)];
  };

  f32x4 acc[8][4];
  #pragma unroll
  for (int i = 0; i < 8; ++i)
    #pragma unroll
    for (int j = 0; j < 4; ++j)
      acc[i][j] = (f32x4){0.f, 0.f, 0.f, 0.f};

  bf16x8 afr[8][2], bfr[2][2];

  // prologue: tile 0 complete + A0,A1,B0 of tile 1 -> vmcnt(6) leaves those 3.
  stage(0, 0, 0, 0); stage(0, 1, 0, 0); stage(1, 0, 0, 0); stage(1, 1, 0, 0);
  if (NTt > 1) {
    stage(0, 0, 1, 1); stage(0, 1, 1, 1); stage(1, 0, 1, 1);
    asm volatile("s_waitcnt vmcnt(6)" ::: "memory");
  } else {
    asm volatile("s_waitcnt vmcnt(0)" ::: "memory");
  }
  BAR();

#define TILE(U, BU) do {                                                       \
    const int u_ = (U);                                                        \
    /* ---- p1: issue A[m0-3]+B[n0-1] reads; stage B1(u+1); BAR; MFMA Q0 --- */\
    _Pragma("unroll")                                                          \
    for (int mi = 0; mi < 4; ++mi) {                                           \
      afr[mi][0] = ldA(BU, mi, 0); afr[mi][1] = ldA(BU, mi, 1);                \
    }                                                                          \
    _Pragma("unroll")                                                          \
    for (int nj = 0; nj < 2; ++nj) {                                           \
      bfr[nj][0] = ldB(BU, nj, 0); bfr[nj][1] = ldB(BU, nj, 1);                \
    }                                                                          \
    if (u_ + 1 < NTt) stage(1, 1, 1 - (BU), u_ + 1);                           \
    asm volatile("s_waitcnt lgkmcnt(8)" ::: "memory");                         \
    BAR();                                                                     \
    WAITL0();                                                                  \
    __builtin_amdgcn_s_setprio(1);                                             \
    _Pragma("unroll")                                                          \
    for (int mi = 0; mi < 4; ++mi)                                             \
      _Pragma("unroll")                                                        \
      for (int nj = 0; nj < 2; ++nj) {                                         \
        acc[mi][nj] = __builtin_amdgcn_mfma_f32_16x16x32_bf16(                 \
            afr[mi][0], bfr[nj][0], acc[mi][nj], 0, 0, 0);                     \
        acc[mi][nj] = __builtin_amdgcn_mfma_f32_16x16x32_bf16(                 \
            afr[mi][1], bfr[nj][1], acc[mi][nj], 0, 0, 0);                     \
      }                                                                        \
    __builtin_amdgcn_s_setprio(0);                                             \
    BAR();                                                                     \
    /* ---- p2: issue A[m4-7]; BAR; MFMA Q1 (A regions retire here) ---- */    \
    _Pragma("unroll")                                                          \
    for (int mi = 4; mi < 8; ++mi) {                                           \
      afr[mi][0] = ldA(BU, mi, 0); afr[mi][1] = ldA(BU, mi, 1);                \
    }                                                                          \
    BAR();                                                                     \
    WAITL0();                                                                  \
    __builtin_amdgcn_s_setprio(1);                                             \
    _Pragma("unroll")                                                          \
    for (int mi = 4; mi < 8; ++mi)                                             \
      _Pragma("unroll")                                                        \
      for (int nj = 0; nj < 2; ++nj) {                                         \
        acc[mi][nj] = __builtin_amdgcn_mfma_f32_16x16x32_bf16(                 \
            afr[mi][0], bfr[nj][0], acc[mi][nj], 0, 0, 0);                     \
        acc[mi][nj] = __builtin_amdgcn_mfma_f32_16x16x32_bf16(                 \
            afr[mi][1], bfr[nj][1], acc[mi][nj], 0, 0, 0);                     \
      }                                                                        \
    __builtin_amdgcn_s_setprio(0);                                             \
    BAR();                                                                     \
    /* ---- p3: issue B[n2-3]; stage A0(u+2) (A dead); BAR; MFMA Q2 ---- */    \
    _Pragma("unroll")                                                          \
    for (int nj = 0; nj < 2; ++nj) {                                           \
      bfr[nj][0] = ldB(BU, 2 + nj, 0); bfr[nj][1] = ldB(BU, 2 + nj, 1);        \
    }                                                                          \
    if (u_ + 2 < NTt) stage(0, 0, BU, u_ + 2);                                 \
    BAR();                                                                     \
    WAITL0();                                                                  \
    __builtin_amdgcn_s_setprio(1);                                             \
    _Pragma("unroll")                                                          \
    for (int mi = 0; mi < 4; ++mi)                                             \
      _Pragma("unroll")                                                        \
      for (int nj = 0; nj < 2; ++nj) {                                         \
        acc[mi][2 + nj] = __builtin_amdgcn_mfma_f32_16x16x32_bf16(             \
            afr[mi][0], bfr[nj][0], acc[mi][2 + nj], 0, 0, 0);                 \
        acc[mi][2 + nj] = __builtin_amdgcn_mfma_f32_16x16x32_bf16(             \
            afr[mi][1], bfr[nj][1], acc[mi][2 + nj], 0, 0, 0);                 \
      }                                                                        \
    __builtin_amdgcn_s_setprio(0);                                             \
    BAR();                                                                     \
    /* ---- p4: stage A1,B0(u+2) (B dead); MFMA Q3 (regs only); vmcnt ---- */  \
    if (u_ + 2 < NTt) { stage(0, 1, BU, u_ + 2); stage(1, 0, BU, u_ + 2); }    \
    __builtin_amdgcn_s_setprio(1);                                             \
    _Pragma("unroll")                                                          \
    for (int mi = 4; mi < 8; ++mi)                                             \
      _Pragma("unroll")                                                        \
      for (int nj = 0; nj < 2; ++nj) {                                         \
        acc[mi][2 + nj] = __builtin_amdgcn_mfma_f32_16x16x32_bf16(             \
            afr[mi][0], bfr[nj][0], acc[mi][2 + nj], 0, 0, 0);                 \
        acc[mi][2 + nj] = __builtin_amdgcn_mfma_f32_16x16x32_bf16(             \
            afr[mi][1], bfr[nj][1], acc[mi][2 + nj], 0, 0, 0);                 \
      }                                                                        \
    __builtin_amdgcn_s_setprio(0);                                             \
    if (u_ + 2 < NTt) asm volatile("s_waitcnt vmcnt(6)" ::: "memory");         \
    else              asm volatile("s_waitcnt vmcnt(0)" ::: "memory");         \
    BAR();                                                                     \
  } while (0)

  for (int u = 0; u < NTt; u += 2) {
    TILE(u, 0);
    TILE(u + 1, 1);
  }
#undef TILE

  // ---- LDS-coalesced epilogue: (x+bias)*0.1, full-line f32x4 stores ----
  float* scratch = (float*)&lds[0][0][0][0];   // 32768 f32 = 128 x 256
  #pragma unroll
  for (int p = 0; p < 2; ++p) {
    if (wr == p) {
      #pragma unroll
      for (int ni = 0; ni < 4; ++ni) {
        const int col = (wc << 6) + ni * 16 + r;
        const float bv = bias[n0 + col];
        #pragma unroll
        for (int mi = 0; mi < 8; ++mi) {
          #pragma unroll
          for (int e = 0; e < 4; ++e) {
            const int row = mi * 16 + (q << 2) + e;
            const int cs  = col ^ (((row >> 2) & 1) << 4);
            scratch[row * 256 + cs] = (acc[mi][ni][e] + bv) * 0.1f;
          }
        }
      }
    }
    __syncthreads();
    #pragma unroll
    for (int rowi = 0; rowi < 16; ++rowi) {
      const int row = (wave << 4) + rowi;
      const int cb  = (lane << 2) ^ (((row >> 2) & 1) << 4);
      const f32x4 v4 = *(const f32x4*)&scratch[row * 256 + cb];
      *(f32x4*)&out[(size_t)(m0 + (p << 7) + row) * ldOut + n0 + (lane << 2)] = v4;
    }
    __syncthreads();
  }
}

// ---------------- LayerNorm over last dim (1024), f32 in -> bf16 out ----------------
__global__ void ln_kernel(const float* __restrict__ merged,
                          const float* __restrict__ lnw,
                          const float* __restrict__ lnb,
                          unsigned short* __restrict__ normed) {
  const int row = blockIdx.x;
  const float4 v = ((const float4*)(merged + (size_t)row * HIDDEN))[threadIdx.x];
  float s  = v.x + v.y + v.z + v.w;
  float ss = v.x * v.x + v.y * v.y + v.z * v.z + v.w * v.w;
  #pragma unroll
  for (int off = 32; off > 0; off >>= 1) {
    s  += __shfl_down(s, off, 64);
    ss += __shfl_down(ss, off, 64);
  }
  __shared__ float red[8];
  const int wvi = threadIdx.x >> 6;
  if ((threadIdx.x & 63) == 0) { red[wvi] = s; red[4 + wvi] = ss; }
  __syncthreads();
  s  = red[0] + red[1] + red[2] + red[3];
  ss = red[4] + red[5] + red[6] + red[7];
  const float mu  = s * (1.0f / HIDDEN);
  const float var = ss * (1.0f / HIDDEN) - mu * mu;
  const float rs  = rsqrtf(var + 1e-5f);
  const float4 w4 = ((const float4*)lnw)[threadIdx.x];
  const float4 b4 = ((const float4*)lnb)[threadIdx.x];
  ushort4 o;
  o.x = f2b((v.x - mu) * rs * w4.x + b4.x);
  o.y = f2b((v.y - mu) * rs * w4.y + b4.y);
  o.z = f2b((v.z - mu) * rs * w4.z + b4.z);
  o.w = f2b((v.w - mu) * rs * w4.w + b4.w);
  ((ushort4*)(normed + (size_t)row * HIDDEN))[threadIdx.x] = o;
}

extern "C" void kernel_launch(void* const* d_in, const int* in_sizes, int n_in,
                              void* d_out, int out_size, void* d_ws, size_t ws_size,
                              hipStream_t stream) {
  const int*   tokens = (const int*)d_in[0];
  const float* E      = (const float*)d_in[1];
  const float* Wc     = (const float*)d_in[2];
  const float* bc     = (const float*)d_in[3];
  const float* Wh     = (const float*)d_in[4];
  const float* bh     = (const float*)d_in[5];
  const float* Wm     = (const float*)d_in[6];
  const float* bm     = (const float*)d_in[7];
  const float* Wo     = (const float*)d_in[8];
  const float* bo     = (const float*)d_in[9];
  const float* lnw    = (const float*)d_in[10];
  const float* lnb    = (const float*)d_in[11];

  char* p = (char*)d_ws;
  unsigned short* WcT  = (unsigned short*)p; p += (size_t)HIDDEN * EMBED * 2;
  unsigned short* WhT  = (unsigned short*)p; p += (size_t)HIDDEN * EMBED * 2;
  unsigned short* WmT  = (unsigned short*)p; p += (size_t)HIDDEN * (2 * HIDDEN) * 2;
  unsigned short* WoT  = (unsigned short*)p; p += (size_t)VOCAB * HIDDEN * 2;
  unsigned short* emb  = (unsigned short*)p; p += (size_t)NROWS * EMBED * 2;
  unsigned short* hist = (unsigned short*)p; p += (size_t)NROWS * EMBED * 2;
  unsigned short* cat  = (unsigned short*)p; p += (size_t)NROWS * (2 * HIDDEN) * 2;
  float*          mrg  = (float*)p;          p += (size_t)NROWS * HIDDEN * 4;
  unsigned short* nrm  = (unsigned short*)p; p += (size_t)NROWS * HIDDEN * 2;
  float*          csum = (float*)p;          p += (size_t)BATCH * NCHUNK * EMBED * 4;
  if ((size_t)(p - (char*)d_ws) > ws_size)
    fprintf(stderr, "WS TOO SMALL: need %zu have %zu\n", (size_t)(p - (char*)d_ws), ws_size);

  // all 4 weight transposes in one launch
  transpose_all_kernel<<<8768, 256, 0, stream>>>(Wc, Wh, Wm, Wo, WcT, WhT, WmT, WoT);

  gather_sum_kernel<<<BATCH * NCHUNK, EMBED, 0, stream>>>(tokens, E, emb, csum);
  scan_excl_kernel<<<dim3(BATCH, EMBED / 128), 128, 0, stream>>>(csum);
  scan_emit_kernel<<<BATCH * NCHUNK, EMBED, 0, stream>>>(emb, csum, hist);

  const int nwgEnc = (NROWS / BM) * (HIDDEN / BN);   // 256 tiles per slice

  // cur_enc / hist_enc fused into one launch (z=2) -> concatenated [4096, 2048] bf16
  gemm_bt_kernel<0><<<dim3(nwgEnc, 1, 2), 256, 0, stream>>>(
      emb, WcT, bc, cat, NROWS, HIDDEN, EMBED, 2 * HIDDEN, 0,
      hist, WhT, bh, HIDDEN);
  // merged = relu(cat @ Wm + bm), kept f32 for LN accuracy
  gemm_bt_kernel<1><<<dim3(nwgEnc, 1, 1), 256, 0, stream>>>(
      cat, WmT, bm, mrg, NROWS, HIDDEN, 2 * HIDDEN, HIDDEN, 0,
      nullptr, nullptr, nullptr, 0);
  ln_kernel<<<NROWS, 256, 0, stream>>>(mrg, lnw, lnb, nrm);

  // logits = (normed @ Wo + bo) * 0.1 -> d_out f32, 256^2 deep-pipelined kernel
  const int nwgOut = (NROWS / 256) * (VOCAB / 256);  // 16 * 125 = 2000
  gemm256_out_kernel<<<dim3(nwgOut), 512, 0, stream>>>(
      nrm, WoT, bo, (float*)d_out, NROWS, VOCAB, HIDDEN, VOCAB);
}

// Round 6
// 941.083 us; speedup vs baseline: 1.1449x; 1.0546x over previous
//
#include <hip/hip_runtime.h>
#include <hip/hip_bf16.h>
#include <stdint.h>
#include <stdio.h>

// Problem dims (fixed by the reference)
#define T_SEQ  2048
#define BATCH  2
#define NROWS  4096   // B*T
#define EMBED  512
#define HIDDEN 1024
#define VOCAB  32000
#define NCHUNK 128
#define CHLEN  16     // T_SEQ / NCHUNK

typedef __bf16 bf16x8 __attribute__((ext_vector_type(8)));
typedef float  f32x4  __attribute__((ext_vector_type(4)));

__device__ __forceinline__ float b2f(unsigned short h) {
  union { unsigned int u; float f; } v; v.u = ((unsigned int)h) << 16; return v.f;
}
__device__ __forceinline__ unsigned short f2b(float f) {
  union { float f; unsigned int u; } v; v.f = f;
  unsigned int u = v.u;
  u += 0x7fffu + ((u >> 16) & 1u);   // round-to-nearest-even
  return (unsigned short)(u >> 16);
}

// -------- fused gather + chunk-sum: emb = bf16(E[tok]); csum[bc] = Σ chunk --------
__global__ void gather_sum_kernel(const int* __restrict__ tokens,
                                  const float* __restrict__ E,
                                  unsigned short* __restrict__ emb,
                                  float* __restrict__ csum) {
  const int bc = blockIdx.x;               // b*NCHUNK + c  (256 blocks)
  const int d  = threadIdx.x;              // 0..511
  __shared__ int tok[CHLEN];
  if (d < CHLEN) tok[d] = tokens[bc * CHLEN + d];
  __syncthreads();
  float s = 0.f;
  unsigned short* eo = emb + ((size_t)bc * CHLEN) * EMBED + d;
  #pragma unroll 4
  for (int i = 0; i < CHLEN; ++i) {
    const float v = E[(size_t)tok[i] * EMBED + d];
    const unsigned short h = f2b(v);
    eo[(size_t)i * EMBED] = h;
    s += b2f(h);                           // bf16-rounded accumulation (matches emit)
  }
  csum[(size_t)bc * EMBED + d] = s;
}

// -------- exclusive scan over chunks: LDS column scan (no serial HBM trips) -----
__global__ void scan_excl_kernel(float* __restrict__ csum) {
  const int b  = blockIdx.x;
  const int d0 = blockIdx.y << 7;
  const int t  = threadIdx.x;
  __shared__ float s[NCHUNK][128];         // 64 KB
  for (int c = 0; c < NCHUNK; ++c)
    s[c][t] = csum[((size_t)b * NCHUNK + c) * EMBED + d0 + t];
  float run = 0.f;                         // column-private: no sync needed
  for (int c = 0; c < NCHUNK; ++c) {
    const float v = s[c][t];
    csum[((size_t)b * NCHUNK + c) * EMBED + d0 + t] = run;
    run += v;
  }
}

__global__ void scan_emit_kernel(const unsigned short* __restrict__ emb,
                                 const float* __restrict__ csum,
                                 unsigned short* __restrict__ hist) {
  const int bc = blockIdx.x;                 // b*NCHUNK + c  (256 blocks)
  const int c  = bc & (NCHUNK - 1);
  const int d  = threadIdx.x;
  const unsigned short* e = emb  + ((size_t)bc * CHLEN) * EMBED + d;
  unsigned short*       h = hist + ((size_t)bc * CHLEN) * EMBED + d;
  float sum = csum[(size_t)bc * EMBED + d];  // exclusive prefix
  #pragma unroll 8
  for (int i = 0; i < CHLEN; ++i) {
    const int t = c * CHLEN + i;
    h[(size_t)i * EMBED] = (t == 0) ? e[0] : f2b(sum / (float)t);
    sum += b2f(e[(size_t)i * EMBED]);
  }
}

// -------- single-launch transpose+cast for all 4 weights, 64x64 f32 tiles --------
__global__ __launch_bounds__(256) void transpose_all_kernel(
    const float* __restrict__ Wc, const float* __restrict__ Wh,
    const float* __restrict__ Wm, const float* __restrict__ Wo,
    unsigned short* __restrict__ WcT, unsigned short* __restrict__ WhT,
    unsigned short* __restrict__ WmT, unsigned short* __restrict__ WoT) {
  const int id = blockIdx.x;
  const float* in; unsigned short* out; int R, C, t;
  if (id < 128)      { in = Wc; out = WcT; R = 512;  C = 1024;  t = id; }
  else if (id < 256) { in = Wh; out = WhT; R = 512;  C = 1024;  t = id - 128; }
  else if (id < 768) { in = Wm; out = WmT; R = 2048; C = 1024;  t = id - 256; }
  else               { in = Wo; out = WoT; R = 1024; C = 32000; t = id - 768; }
  const int tilesX = C >> 6;
  const int r0 = (t / tilesX) << 6, c0 = (t % tilesX) << 6;

  __shared__ float tile[64][65];
  const int tid = threadIdx.x;
  #pragma unroll
  for (int p = 0; p < 4; ++p) {
    const int u = tid + p * 256;
    const int row = u >> 4, cq = (u & 15) << 2;
    const float4 v = *(const float4*)&in[(size_t)(r0 + row) * C + c0 + cq];
    tile[row][cq + 0] = v.x; tile[row][cq + 1] = v.y;
    tile[row][cq + 2] = v.z; tile[row][cq + 3] = v.w;
  }
  __syncthreads();
  #pragma unroll
  for (int p = 0; p < 4; ++p) {
    const int u = tid + p * 256;
    const int oc = u >> 4, org = (u & 15) << 2;
    ushort4 o;
    o.x = f2b(tile[org + 0][oc]); o.y = f2b(tile[org + 1][oc]);
    o.z = f2b(tile[org + 2][oc]); o.w = f2b(tile[org + 3][oc]);
    *(ushort4*)&out[(size_t)(c0 + oc) * R + r0 + org] = o;
  }
}

__device__ __forceinline__ void async16(unsigned short* lds, const unsigned short* g) {
  __builtin_amdgcn_global_load_lds(
      (const __attribute__((address_space(1))) void*)g,
      (__attribute__((address_space(3))) void*)lds, 16, 0, 0);
}

// ---------------- 128x128 MFMA GEMM (encode / merge) ----------------
// MODE 0: relu -> bf16 ; MODE 1: relu -> f32
#define BM 128
#define BN 128
#define BK 32

template<int MODE>
__global__ __launch_bounds__(256) void gemm_bt_kernel(
    const unsigned short* __restrict__ A,
    const unsigned short* __restrict__ BT,
    const float* __restrict__ bias,
    void* __restrict__ out, int M, int N, int K, int ldOut, int colOff,
    const unsigned short* __restrict__ A2,
    const unsigned short* __restrict__ BT2,
    const float* __restrict__ bias2, int colOff2) {
  __shared__ unsigned short As[BM * BK];
  __shared__ unsigned short Bs[BN * BK];

  const unsigned short* Ap = A;
  const unsigned short* Bp = BT;
  const float*          bp = bias;
  int                   co = colOff;
  if (blockIdx.z) { Ap = A2; Bp = BT2; bp = bias2; co = colOff2; }

  int wg = blockIdx.x;
  {
    const int nwg = gridDim.x;
    const int xcd = wg & 7, loc = wg >> 3;
    const int q = nwg >> 3, r = nwg & 7;
    wg = (xcd < r ? xcd * (q + 1) : r * (q + 1) + (xcd - r) * q) + loc;
  }
  const int nmb = M / BM;
  const int mb  = wg % nmb;
  const int nb  = wg / nmb;
  const int m0  = mb * BM;
  const int n0  = nb * BN;

  const int tid  = threadIdx.x;
  const int wave = tid >> 6;
  const int lane = tid & 63;
  const int wm = (wave & 1) * 64;
  const int wn = (wave >> 1) * 64;

  const int srow = (wave << 5) + (lane >> 2);
  const int scol = (lane & 3) << 3;
  const unsigned short* aSrc = Ap + (size_t)(m0 + srow) * K + scol;
  const unsigned short* bSrc = Bp + (size_t)(n0 + srow) * K + scol;
  unsigned short* aDst = As + (wave << 5) * BK;
  unsigned short* bDst = Bs + (wave << 5) * BK;

  f32x4 acc[4][4];
  #pragma unroll
  for (int i = 0; i < 4; ++i)
    #pragma unroll
    for (int j = 0; j < 4; ++j)
      acc[i][j] = (f32x4){0.f, 0.f, 0.f, 0.f};

  const int q = lane >> 4;
  const int r = lane & 15;

  for (int k0 = 0; k0 < K; k0 += BK) {
    __syncthreads();
    async16(aDst,           aSrc);
    async16(aDst + 16 * BK, aSrc + 16 * (size_t)K);
    async16(bDst,           bSrc);
    async16(bDst + 16 * BK, bSrc + 16 * (size_t)K);
    aSrc += BK; bSrc += BK;
    __syncthreads();

    bf16x8 af[4], bfr[4];
    #pragma unroll
    for (int mi = 0; mi < 4; ++mi)
      af[mi] = *(const bf16x8*)&As[(wm + mi * 16 + r) * BK + (q << 3)];
    #pragma unroll
    for (int ni = 0; ni < 4; ++ni)
      bfr[ni] = *(const bf16x8*)&Bs[(wn + ni * 16 + r) * BK + (q << 3)];
    #pragma unroll
    for (int mi = 0; mi < 4; ++mi)
      #pragma unroll
      for (int ni = 0; ni < 4; ++ni)
        acc[mi][ni] = __builtin_amdgcn_mfma_f32_16x16x32_bf16(
            af[mi], bfr[ni], acc[mi][ni], 0, 0, 0);
  }

  #pragma unroll
  for (int ni = 0; ni < 4; ++ni) {
    const int col = n0 + wn + ni * 16 + r;
    const float bv = bp[col];
    #pragma unroll
    for (int mi = 0; mi < 4; ++mi) {
      #pragma unroll
      for (int e = 0; e < 4; ++e) {
        const int row = m0 + wm + mi * 16 + (q << 2) + e;
        float v = fmaxf(acc[mi][ni][e] + bv, 0.f);
        const size_t idx = (size_t)row * ldOut + co + col;
        if (MODE == 0) ((unsigned short*)out)[idx] = f2b(v);
        else           ((float*)out)[idx] = v;
      }
    }
  }
}

// ============ 256x256 8-wave deep-pipelined GEMM (logits) ============
// Round-3 EXACT main loop (best measured: fused phases, 0 bank conflicts,
// counted vmcnt(6)). ONE change vs r3: epilogue stores are NON-TEMPORAL
// full-128B-line f32x4 — the 516 MB logits write stream no longer evicts
// the B-panels from L2/L3 (that eviction was the 5x HBM over-fetch).

#define BAR() do {                            \
    asm volatile("" ::: "memory");            \
    __builtin_amdgcn_sched_barrier(0);        \
    __builtin_amdgcn_s_barrier();             \
    __builtin_amdgcn_sched_barrier(0);        \
    asm volatile("" ::: "memory");            \
  } while (0)

__global__ __launch_bounds__(512, 2) void gemm256_out_kernel(
    const unsigned short* __restrict__ A,
    const unsigned short* __restrict__ BT,
    const float* __restrict__ bias,
    float* __restrict__ out, int M, int N, int K, int ldOut) {
  // [buf][mat A=0/B=1][half][128 rows * 64 cols]
  __shared__ unsigned short lds[2][2][2][8192];

  int wg = blockIdx.x;
  {
    const int nwg = gridDim.x;
    const int xcd = wg & 7, loc = wg >> 3;
    const int q8 = nwg >> 3, r8 = nwg & 7;
    wg = (xcd < r8 ? xcd * (q8 + 1) : r8 * (q8 + 1) + (xcd - r8) * q8) + loc;
  }
  const int nmb = M >> 8;
  const int mb = wg % nmb, nb = wg / nmb;
  const int m0 = mb << 8, n0 = nb << 8;

  const int tid  = threadIdx.x;
  const int wave = tid >> 6, lane = tid & 63;
  const int wr = wave >> 2, wc = wave & 3;     // 2x4 wave grid; per-wave out 128x64
  const int q = lane >> 4, r = lane & 15, rr = lane & 7;

  const int srow = (wave << 4) + (lane >> 3);          // row within half
  const int scol = ((lane & 7) ^ (lane >> 3)) << 3;    // inverse-swizzled src col
  const unsigned short* aB = A  + (size_t)(m0 + srow) * K + scol;
  const unsigned short* bB = BT + (size_t)(n0 + srow) * K + scol;

  const int NTt = K >> 6;  // K-tiles of 64

  auto stage = [&](int matB, int h, int tb, int kt) {
    unsigned short* d = &lds[tb][matB][h][wave << 10];
    const unsigned short* s =
        (matB ? bB : aB) + (size_t)h * 128 * K + ((size_t)kt << 6);
    async16(d, s);
    async16(d + 512, s + ((size_t)K << 3));
  };

  auto ldA = [&](int tb, int mi, int ks) {
    return *(const bf16x8*)&lds[tb][0][wr]
        [(mi * 16 + r) * 64 + ((((ks << 2) | q) ^ rr) << 3)];
  };
  auto ldB = [&](int tb, int ni, int ks) {
    return *(const bf16x8*)&lds[tb][1][wc >> 1]
        [(((wc & 1) << 6) + ni * 16 + r) * 64 + ((((ks << 2) | q) ^ rr) << 3)];
  };

  f32x4 acc[8][4];
  #pragma unroll
  for (int i = 0; i < 8; ++i)
    #pragma unroll
    for (int j = 0; j < 4; ++j)
      acc[i][j] = (f32x4){0.f, 0.f, 0.f, 0.f};

  bf16x8 afr[8][2], bfr[2][2];

  // prologue: tile 0 complete + A0,A1,B0 of tile 1 -> vmcnt(6) leaves those 3.
  stage(0, 0, 0, 0); stage(0, 1, 0, 0); stage(1, 0, 0, 0); stage(1, 1, 0, 0);
  if (NTt > 1) {
    stage(0, 0, 1, 1); stage(0, 1, 1, 1); stage(1, 0, 1, 1);
    asm volatile("s_waitcnt vmcnt(6)" ::: "memory");
  } else {
    asm volatile("s_waitcnt vmcnt(0)" ::: "memory");
  }
  BAR();

#define TILE(U, BU) do {                                                       \
    const int u_ = (U);                                                        \
    /* ---- p1: A[m0-3], B[n0-1]; stage B1(u+1) ---- */                        \
    _Pragma("unroll")                                                          \
    for (int mi = 0; mi < 4; ++mi) {                                           \
      afr[mi][0] = ldA(BU, mi, 0); afr[mi][1] = ldA(BU, mi, 1);                \
    }                                                                          \
    _Pragma("unroll")                                                          \
    for (int nj = 0; nj < 2; ++nj) {                                           \
      bfr[nj][0] = ldB(BU, nj, 0); bfr[nj][1] = ldB(BU, nj, 1);                \
    }                                                                          \
    if (u_ + 1 < NTt) stage(1, 1, 1 - (BU), u_ + 1);                           \
    __builtin_amdgcn_s_setprio(1);                                             \
    _Pragma("unroll")                                                          \
    for (int mi = 0; mi < 4; ++mi)                                             \
      _Pragma("unroll")                                                        \
      for (int nj = 0; nj < 2; ++nj) {                                         \
        acc[mi][nj] = __builtin_amdgcn_mfma_f32_16x16x32_bf16(                 \
            afr[mi][0], bfr[nj][0], acc[mi][nj], 0, 0, 0);                     \
        acc[mi][nj] = __builtin_amdgcn_mfma_f32_16x16x32_bf16(                 \
            afr[mi][1], bfr[nj][1], acc[mi][nj], 0, 0, 0);                     \
      }                                                                        \
    __builtin_amdgcn_s_setprio(0);                                             \
    BAR();                                                                     \
    /* ---- p2: A[m4-7] (A regions retire) ---- */                             \
    _Pragma("unroll")                                                          \
    for (int mi = 4; mi < 8; ++mi) {                                           \
      afr[mi][0] = ldA(BU, mi, 0); afr[mi][1] = ldA(BU, mi, 1);                \
    }                                                                          \
    __builtin_amdgcn_s_setprio(1);                                             \
    _Pragma("unroll")                                                          \
    for (int mi = 4; mi < 8; ++mi)                                             \
      _Pragma("unroll")                                                        \
      for (int nj = 0; nj < 2; ++nj) {                                         \
        acc[mi][nj] = __builtin_amdgcn_mfma_f32_16x16x32_bf16(                 \
            afr[mi][0], bfr[nj][0], acc[mi][nj], 0, 0, 0);                     \
        acc[mi][nj] = __builtin_amdgcn_mfma_f32_16x16x32_bf16(                 \
            afr[mi][1], bfr[nj][1], acc[mi][nj], 0, 0, 0);                     \
      }                                                                        \
    __builtin_amdgcn_s_setprio(0);                                             \
    BAR();                                                                     \
    /* ---- p3: B[n2-3]; stage A0(u+2) (A dead) ---- */                        \
    _Pragma("unroll")                                                          \
    for (int nj = 0; nj < 2; ++nj) {                                           \
      bfr[nj][0] = ldB(BU, 2 + nj, 0); bfr[nj][1] = ldB(BU, 2 + nj, 1);        \
    }                                                                          \
    if (u_ + 2 < NTt) stage(0, 0, BU, u_ + 2);                                 \
    __builtin_amdgcn_s_setprio(1);                                             \
    _Pragma("unroll")                                                          \
    for (int mi = 0; mi < 4; ++mi)                                             \
      _Pragma("unroll")                                                        \
      for (int nj = 0; nj < 2; ++nj) {                                         \
        acc[mi][2 + nj] = __builtin_amdgcn_mfma_f32_16x16x32_bf16(             \
            afr[mi][0], bfr[nj][0], acc[mi][2 + nj], 0, 0, 0);                 \
        acc[mi][2 + nj] = __builtin_amdgcn_mfma_f32_16x16x32_bf16(             \
            afr[mi][1], bfr[nj][1], acc[mi][2 + nj], 0, 0, 0);                 \
      }                                                                        \
    __builtin_amdgcn_s_setprio(0);                                             \
    BAR();                                                                     \
    /* ---- p4: stage A1,B0(u+2) (B dead); counted vmcnt ---- */               \
    if (u_ + 2 < NTt) { stage(0, 1, BU, u_ + 2); stage(1, 0, BU, u_ + 2); }    \
    __builtin_amdgcn_s_setprio(1);                                             \
    _Pragma("unroll")                                                          \
    for (int mi = 4; mi < 8; ++mi)                                             \
      _Pragma("unroll")                                                        \
      for (int nj = 0; nj < 2; ++nj) {                                         \
        acc[mi][2 + nj] = __builtin_amdgcn_mfma_f32_16x16x32_bf16(             \
            afr[mi][0], bfr[nj][0], acc[mi][2 + nj], 0, 0, 0);                 \
        acc[mi][2 + nj] = __builtin_amdgcn_mfma_f32_16x16x32_bf16(             \
            afr[mi][1], bfr[nj][1], acc[mi][2 + nj], 0, 0, 0);                 \
      }                                                                        \
    __builtin_amdgcn_s_setprio(0);                                             \
    if (u_ + 2 < NTt) asm volatile("s_waitcnt vmcnt(6)" ::: "memory");         \
    else              asm volatile("s_waitcnt vmcnt(0)" ::: "memory");         \
    BAR();                                                                     \
  } while (0)

  for (int u = 0; u < NTt; u += 2) {
    TILE(u, 0);
    TILE(u + 1, 1);
  }
#undef TILE

  // ---- LDS-coalesced epilogue: (x+bias)*0.1, full-line NON-TEMPORAL stores ----
  float* scratch = (float*)&lds[0][0][0][0];   // 32768 f32 = 128 x 256
  #pragma unroll
  for (int p = 0; p < 2; ++p) {
    if (wr == p) {
      #pragma unroll
      for (int ni = 0; ni < 4; ++ni) {
        const int col = (wc << 6) + ni * 16 + r;
        const float bv = bias[n0 + col];
        #pragma unroll
        for (int mi = 0; mi < 8; ++mi) {
          #pragma unroll
          for (int e = 0; e < 4; ++e) {
            const int row = mi * 16 + (q << 2) + e;
            const int cs  = col ^ (((row >> 2) & 1) << 4);
            scratch[row * 256 + cs] = (acc[mi][ni][e] + bv) * 0.1f;
          }
        }
      }
    }
    __syncthreads();
    #pragma unroll
    for (int rowi = 0; rowi < 16; ++rowi) {
      const int row = (wave << 4) + rowi;
      const int cb  = (lane << 2) ^ (((row >> 2) & 1) << 4);
      const f32x4 v4 = *(const f32x4*)&scratch[row * 256 + cb];
      __builtin_nontemporal_store(
          v4, (f32x4*)&out[(size_t)(m0 + (p << 7) + row) * ldOut + n0 + (lane << 2)]);
    }
    __syncthreads();
  }
}

// ---------------- LayerNorm over last dim (1024), f32 in -> bf16 out ----------------
__global__ void ln_kernel(const float* __restrict__ merged,
                          const float* __restrict__ lnw,
                          const float* __restrict__ lnb,
                          unsigned short* __restrict__ normed) {
  const int row = blockIdx.x;
  const float4 v = ((const float4*)(merged + (size_t)row * HIDDEN))[threadIdx.x];
  float s  = v.x + v.y + v.z + v.w;
  float ss = v.x * v.x + v.y * v.y + v.z * v.z + v.w * v.w;
  #pragma unroll
  for (int off = 32; off > 0; off >>= 1) {
    s  += __shfl_down(s, off, 64);
    ss += __shfl_down(ss, off, 64);
  }
  __shared__ float red[8];
  const int wvi = threadIdx.x >> 6;
  if ((threadIdx.x & 63) == 0) { red[wvi] = s; red[4 + wvi] = ss; }
  __syncthreads();
  s  = red[0] + red[1] + red[2] + red[3];
  ss = red[4] + red[5] + red[6] + red[7];
  const float mu  = s * (1.0f / HIDDEN);
  const float var = ss * (1.0f / HIDDEN) - mu * mu;
  const float rs  = rsqrtf(var + 1e-5f);
  const float4 w4 = ((const float4*)lnw)[threadIdx.x];
  const float4 b4 = ((const float4*)lnb)[threadIdx.x];
  ushort4 o;
  o.x = f2b((v.x - mu) * rs * w4.x + b4.x);
  o.y = f2b((v.y - mu) * rs * w4.y + b4.y);
  o.z = f2b((v.z - mu) * rs * w4.z + b4.z);
  o.w = f2b((v.w - mu) * rs * w4.w + b4.w);
  ((ushort4*)(normed + (size_t)row * HIDDEN))[threadIdx.x] = o;
}

extern "C" void kernel_launch(void* const* d_in, const int* in_sizes, int n_in,
                              void* d_out, int out_size, void* d_ws, size_t ws_size,
                              hipStream_t stream) {
  const int*   tokens = (const int*)d_in[0];
  const float* E      = (const float*)d_in[1];
  const float* Wc     = (const float*)d_in[2];
  const float* bc     = (const float*)d_in[3];
  const float* Wh     = (const float*)d_in[4];
  const float* bh     = (const float*)d_in[5];
  const float* Wm     = (const float*)d_in[6];
  const float* bm     = (const float*)d_in[7];
  const float* Wo     = (const float*)d_in[8];
  const float* bo     = (const float*)d_in[9];
  const float* lnw    = (const float*)d_in[10];
  const float* lnb    = (const float*)d_in[11];

  char* p = (char*)d_ws;
  unsigned short* WcT  = (unsigned short*)p; p += (size_t)HIDDEN * EMBED * 2;
  unsigned short* WhT  = (unsigned short*)p; p += (size_t)HIDDEN * EMBED * 2;
  unsigned short* WmT  = (unsigned short*)p; p += (size_t)HIDDEN * (2 * HIDDEN) * 2;
  unsigned short* WoT  = (unsigned short*)p; p += (size_t)VOCAB * HIDDEN * 2;
  unsigned short* emb  = (unsigned short*)p; p += (size_t)NROWS * EMBED * 2;
  unsigned short* hist = (unsigned short*)p; p += (size_t)NROWS * EMBED * 2;
  unsigned short* cat  = (unsigned short*)p; p += (size_t)NROWS * (2 * HIDDEN) * 2;
  float*          mrg  = (float*)p;          p += (size_t)NROWS * HIDDEN * 4;
  unsigned short* nrm  = (unsigned short*)p; p += (size_t)NROWS * HIDDEN * 2;
  float*          csum = (float*)p;          p += (size_t)BATCH * NCHUNK * EMBED * 4;
  if ((size_t)(p - (char*)d_ws) > ws_size)
    fprintf(stderr, "WS TOO SMALL: need %zu have %zu\n", (size_t)(p - (char*)d_ws), ws_size);

  // all 4 weight transposes in one launch
  transpose_all_kernel<<<8768, 256, 0, stream>>>(Wc, Wh, Wm, Wo, WcT, WhT, WmT, WoT);

  gather_sum_kernel<<<BATCH * NCHUNK, EMBED, 0, stream>>>(tokens, E, emb, csum);
  scan_excl_kernel<<<dim3(BATCH, EMBED / 128), 128, 0, stream>>>(csum);
  scan_emit_kernel<<<BATCH * NCHUNK, EMBED, 0, stream>>>(emb, csum, hist);

  const int nwgEnc = (NROWS / BM) * (HIDDEN / BN);   // 256 tiles per slice

  // cur_enc / hist_enc fused into one launch (z=2) -> concatenated [4096, 2048] bf16
  gemm_bt_kernel<0><<<dim3(nwgEnc, 1, 2), 256, 0, stream>>>(
      emb, WcT, bc, cat, NROWS, HIDDEN, EMBED, 2 * HIDDEN, 0,
      hist, WhT, bh, HIDDEN);
  // merged = relu(cat @ Wm + bm), kept f32 for LN accuracy
  gemm_bt_kernel<1><<<dim3(nwgEnc, 1, 1), 256, 0, stream>>>(
      cat, WmT, bm, mrg, NROWS, HIDDEN, 2 * HIDDEN, HIDDEN, 0,
      nullptr, nullptr, nullptr, 0);
  ln_kernel<<<NROWS, 256, 0, stream>>>(mrg, lnw, lnb, nrm);

  // logits = (normed @ Wo + bo) * 0.1 -> d_out f32, 256^2 deep-pipelined kernel
  const int nwgOut = (NROWS / 256) * (VOCAB / 256);  // 16 * 125 = 2000
  gemm256_out_kernel<<<dim3(nwgOut), 512, 0, stream>>>(
      nrm, WoT, bo, (float*)d_out, NROWS, VOCAB, HIDDEN, VOCAB);
}

// Round 7
// 939.296 us; speedup vs baseline: 1.1471x; 1.0019x over previous
//
#include <hip/hip_runtime.h>
#include <hip/hip_bf16.h>
#include <stdint.h>
#include <stdio.h>

// Problem dims (fixed by the reference)
#define T_SEQ  2048
#define BATCH  2
#define NROWS  4096   // B*T
#define EMBED  512
#define HIDDEN 1024
#define VOCAB  32000
#define NCHUNK 128
#define CHLEN  16     // T_SEQ / NCHUNK

typedef __bf16 bf16x8 __attribute__((ext_vector_type(8)));
typedef float  f32x4  __attribute__((ext_vector_type(4)));

__device__ __forceinline__ float b2f(unsigned short h) {
  union { unsigned int u; float f; } v; v.u = ((unsigned int)h) << 16; return v.f;
}
__device__ __forceinline__ unsigned short f2b(float f) {
  union { float f; unsigned int u; } v; v.f = f;
  unsigned int u = v.u;
  u += 0x7fffu + ((u >> 16) & 1u);   // round-to-nearest-even
  return (unsigned short)(u >> 16);
}

__device__ __forceinline__ void async16(unsigned short* lds, const unsigned short* g) {
  __builtin_amdgcn_global_load_lds(
      (const __attribute__((address_space(1))) void*)g,
      (__attribute__((address_space(3))) void*)lds, 16, 0, 0);
}

// ====== fused prep: 4 weight transposes (blocks 0..8767) + gather_sum (8768..9023) ======
// transpose: 64x64 f32 tiles, float4 loads / ushort4 stores, 512 threads (2 passes).
// gather: emb = bf16(E[tok]); csum[bc] = per-chunk sum (bf16-rounded, matches emit).
__global__ __launch_bounds__(512) void prep_kernel(
    const int* __restrict__ tokens, const float* __restrict__ E,
    unsigned short* __restrict__ emb, float* __restrict__ csum,
    const float* __restrict__ Wc, const float* __restrict__ Wh,
    const float* __restrict__ Wm, const float* __restrict__ Wo,
    unsigned short* __restrict__ WcT, unsigned short* __restrict__ WhT,
    unsigned short* __restrict__ WmT, unsigned short* __restrict__ WoT) {
  const int id = blockIdx.x;

  if (id >= 8768) {                          // ---- gather_sum part ----
    const int bc = id - 8768;                // b*NCHUNK + c  (256 blocks)
    const int d  = threadIdx.x;              // 0..511
    __shared__ int tok[CHLEN];
    if (d < CHLEN) tok[d] = tokens[bc * CHLEN + d];
    __syncthreads();
    float s = 0.f;
    unsigned short* eo = emb + ((size_t)bc * CHLEN) * EMBED + d;
    #pragma unroll 4
    for (int i = 0; i < CHLEN; ++i) {
      const float v = E[(size_t)tok[i] * EMBED + d];
      const unsigned short h = f2b(v);
      eo[(size_t)i * EMBED] = h;
      s += b2f(h);
    }
    csum[(size_t)bc * EMBED + d] = s;
    return;
  }

  // ---- transpose part ----
  const float* in; unsigned short* out; int R, C, t;
  if (id < 128)      { in = Wc; out = WcT; R = 512;  C = 1024;  t = id; }
  else if (id < 256) { in = Wh; out = WhT; R = 512;  C = 1024;  t = id - 128; }
  else if (id < 768) { in = Wm; out = WmT; R = 2048; C = 1024;  t = id - 256; }
  else               { in = Wo; out = WoT; R = 1024; C = 32000; t = id - 768; }
  const int tilesX = C >> 6;
  const int r0 = (t / tilesX) << 6, c0 = (t % tilesX) << 6;

  __shared__ float tile[64][65];
  const int tid = threadIdx.x;
  #pragma unroll
  for (int p = 0; p < 2; ++p) {
    const int u = tid + p * 512;             // 1024 float4 units
    const int row = u >> 4, cq = (u & 15) << 2;
    const float4 v = *(const float4*)&in[(size_t)(r0 + row) * C + c0 + cq];
    tile[row][cq + 0] = v.x; tile[row][cq + 1] = v.y;
    tile[row][cq + 2] = v.z; tile[row][cq + 3] = v.w;
  }
  __syncthreads();
  #pragma unroll
  for (int p = 0; p < 2; ++p) {
    const int u = tid + p * 512;             // 1024 ushort4 units
    const int oc = u >> 4, org = (u & 15) << 2;
    ushort4 o;
    o.x = f2b(tile[org + 0][oc]); o.y = f2b(tile[org + 1][oc]);
    o.z = f2b(tile[org + 2][oc]); o.w = f2b(tile[org + 3][oc]);
    *(ushort4*)&out[(size_t)(c0 + oc) * R + r0 + org] = o;
  }
}

// -------- exclusive scan over chunks: LDS column scan --------
__global__ void scan_excl_kernel(float* __restrict__ csum) {
  const int b  = blockIdx.x;
  const int d0 = blockIdx.y << 7;
  const int t  = threadIdx.x;
  __shared__ float s[NCHUNK][128];         // 64 KB
  for (int c = 0; c < NCHUNK; ++c)
    s[c][t] = csum[((size_t)b * NCHUNK + c) * EMBED + d0 + t];
  float run = 0.f;                         // column-private: no sync needed
  for (int c = 0; c < NCHUNK; ++c) {
    const float v = s[c][t];
    csum[((size_t)b * NCHUNK + c) * EMBED + d0 + t] = run;
    run += v;
  }
}

__global__ void scan_emit_kernel(const unsigned short* __restrict__ emb,
                                 const float* __restrict__ csum,
                                 unsigned short* __restrict__ hist) {
  const int bc = blockIdx.x;                 // b*NCHUNK + c  (256 blocks)
  const int c  = bc & (NCHUNK - 1);
  const int d  = threadIdx.x;
  const unsigned short* e = emb  + ((size_t)bc * CHLEN) * EMBED + d;
  unsigned short*       h = hist + ((size_t)bc * CHLEN) * EMBED + d;
  float sum = csum[(size_t)bc * EMBED + d];  // exclusive prefix
  #pragma unroll 8
  for (int i = 0; i < CHLEN; ++i) {
    const int t = c * CHLEN + i;
    h[(size_t)i * EMBED] = (t == 0) ? e[0] : f2b(sum / (float)t);
    sum += b2f(e[(size_t)i * EMBED]);
  }
}

// ---------------- 128x128 MFMA GEMM (encode / merge) ----------------
// MODE 0: relu -> bf16 ; MODE 1: relu -> f32
// T3-minimum double-buffer: stage(t+1) issued BEFORE tile t's ds_read+MFMA;
// ONE __syncthreads per tile (its implicit vmcnt(0)/lgkmcnt(0) drain lands
// after the compute, so HBM latency hides under the MFMA cluster).
#define BM 128
#define BN 128
#define BK 32

template<int MODE>
__global__ __launch_bounds__(256) void gemm_bt_kernel(
    const unsigned short* __restrict__ A,
    const unsigned short* __restrict__ BT,
    const float* __restrict__ bias,
    void* __restrict__ out, int M, int N, int K, int ldOut, int colOff,
    const unsigned short* __restrict__ A2,
    const unsigned short* __restrict__ BT2,
    const float* __restrict__ bias2, int colOff2) {
  __shared__ unsigned short As[2][BM * BK];   // 16 KB
  __shared__ unsigned short Bs[2][BN * BK];   // 16 KB

  const unsigned short* Ap = A;
  const unsigned short* Bp = BT;
  const float*          bp = bias;
  int                   co = colOff;
  if (blockIdx.z) { Ap = A2; Bp = BT2; bp = bias2; co = colOff2; }

  int wg = blockIdx.x;
  {
    const int nwg = gridDim.x;
    const int xcd = wg & 7, loc = wg >> 3;
    const int q = nwg >> 3, r = nwg & 7;
    wg = (xcd < r ? xcd * (q + 1) : r * (q + 1) + (xcd - r) * q) + loc;
  }
  const int nmb = M / BM;
  const int mb  = wg % nmb;
  const int nb  = wg / nmb;
  const int m0  = mb * BM;
  const int n0  = nb * BN;

  const int tid  = threadIdx.x;
  const int wave = tid >> 6;
  const int lane = tid & 63;
  const int wm = (wave & 1) * 64;
  const int wn = (wave >> 1) * 64;

  const int srow = (wave << 5) + (lane >> 2);
  const int scol = (lane & 3) << 3;
  const unsigned short* aSrc = Ap + (size_t)(m0 + srow) * K + scol;
  const unsigned short* bSrc = Bp + (size_t)(n0 + srow) * K + scol;
  const int ldsOff = (wave << 5) * BK;

  f32x4 acc[4][4];
  #pragma unroll
  for (int i = 0; i < 4; ++i)
    #pragma unroll
    for (int j = 0; j < 4; ++j)
      acc[i][j] = (f32x4){0.f, 0.f, 0.f, 0.f};

  const int q = lane >> 4;
  const int r = lane & 15;

  auto stageT = [&](int buf) {
    async16(&As[buf][ldsOff],           aSrc);
    async16(&As[buf][ldsOff + 16 * BK], aSrc + 16 * (size_t)K);
    async16(&Bs[buf][ldsOff],           bSrc);
    async16(&Bs[buf][ldsOff + 16 * BK], bSrc + 16 * (size_t)K);
    aSrc += BK; bSrc += BK;
  };

  const int nt = K / BK;
  stageT(0);
  __syncthreads();                            // drains prologue staging

  for (int t = 0; t < nt; ++t) {
    const int c = t & 1;
    if (t + 1 < nt) stageT(1 - c);            // issue next tile early (overlaps)

    bf16x8 af[4], bfr[4];
    #pragma unroll
    for (int mi = 0; mi < 4; ++mi)
      af[mi] = *(const bf16x8*)&As[c][(wm + mi * 16 + r) * BK + (q << 3)];
    #pragma unroll
    for (int ni = 0; ni < 4; ++ni)
      bfr[ni] = *(const bf16x8*)&Bs[c][(wn + ni * 16 + r) * BK + (q << 3)];
    #pragma unroll
    for (int mi = 0; mi < 4; ++mi)
      #pragma unroll
      for (int ni = 0; ni < 4; ++ni)
        acc[mi][ni] = __builtin_amdgcn_mfma_f32_16x16x32_bf16(
            af[mi], bfr[ni], acc[mi][ni], 0, 0, 0);

    __syncthreads();   // implicit vmcnt(0)+lgkmcnt(0): next-tile staging complete;
                       // all waves done reading buf c -> safe to restage it at t+2
  }

  #pragma unroll
  for (int ni = 0; ni < 4; ++ni) {
    const int col = n0 + wn + ni * 16 + r;
    const float bv = bp[col];
    #pragma unroll
    for (int mi = 0; mi < 4; ++mi) {
      #pragma unroll
      for (int e = 0; e < 4; ++e) {
        const int row = m0 + wm + mi * 16 + (q << 2) + e;
        float v = fmaxf(acc[mi][ni][e] + bv, 0.f);
        const size_t idx = (size_t)row * ldOut + co + col;
        if (MODE == 0) ((unsigned short*)out)[idx] = f2b(v);
        else           ((float*)out)[idx] = v;
      }
    }
  }
}

// ============ 256x256 8-wave deep-pipelined GEMM (logits) ============
// Round-6 EXACT (best measured): r3 fused phases, 0 bank conflicts, counted
// vmcnt(6), LDS-coalesced NON-TEMPORAL full-line epilogue. FROZEN.

#define BAR() do {                            \
    asm volatile("" ::: "memory");            \
    __builtin_amdgcn_sched_barrier(0);        \
    __builtin_amdgcn_s_barrier();             \
    __builtin_amdgcn_sched_barrier(0);        \
    asm volatile("" ::: "memory");            \
  } while (0)

__global__ __launch_bounds__(512, 2) void gemm256_out_kernel(
    const unsigned short* __restrict__ A,
    const unsigned short* __restrict__ BT,
    const float* __restrict__ bias,
    float* __restrict__ out, int M, int N, int K, int ldOut) {
  // [buf][mat A=0/B=1][half][128 rows * 64 cols]
  __shared__ unsigned short lds[2][2][2][8192];

  int wg = blockIdx.x;
  {
    const int nwg = gridDim.x;
    const int xcd = wg & 7, loc = wg >> 3;
    const int q8 = nwg >> 3, r8 = nwg & 7;
    wg = (xcd < r8 ? xcd * (q8 + 1) : r8 * (q8 + 1) + (xcd - r8) * q8) + loc;
  }
  const int nmb = M >> 8;
  const int mb = wg % nmb, nb = wg / nmb;
  const int m0 = mb << 8, n0 = nb << 8;

  const int tid  = threadIdx.x;
  const int wave = tid >> 6, lane = tid & 63;
  const int wr = wave >> 2, wc = wave & 3;     // 2x4 wave grid; per-wave out 128x64
  const int q = lane >> 4, r = lane & 15, rr = lane & 7;

  const int srow = (wave << 4) + (lane >> 3);          // row within half
  const int scol = ((lane & 7) ^ (lane >> 3)) << 3;    // inverse-swizzled src col
  const unsigned short* aB = A  + (size_t)(m0 + srow) * K + scol;
  const unsigned short* bB = BT + (size_t)(n0 + srow) * K + scol;

  const int NTt = K >> 6;  // K-tiles of 64

  auto stage = [&](int matB, int h, int tb, int kt) {
    unsigned short* d = &lds[tb][matB][h][wave << 10];
    const unsigned short* s =
        (matB ? bB : aB) + (size_t)h * 128 * K + ((size_t)kt << 6);
    async16(d, s);
    async16(d + 512, s + ((size_t)K << 3));
  };

  auto ldA = [&](int tb, int mi, int ks) {
    return *(const bf16x8*)&lds[tb][0][wr]
        [(mi * 16 + r) * 64 + ((((ks << 2) | q) ^ rr) << 3)];
  };
  auto ldB = [&](int tb, int ni, int ks) {
    return *(const bf16x8*)&lds[tb][1][wc >> 1]
        [(((wc & 1) << 6) + ni * 16 + r) * 64 + ((((ks << 2) | q) ^ rr) << 3)];
  };

  f32x4 acc[8][4];
  #pragma unroll
  for (int i = 0; i < 8; ++i)
    #pragma unroll
    for (int j = 0; j < 4; ++j)
      acc[i][j] = (f32x4){0.f, 0.f, 0.f, 0.f};

  bf16x8 afr[8][2], bfr[2][2];

  // prologue: tile 0 complete + A0,A1,B0 of tile 1 -> vmcnt(6) leaves those 3.
  stage(0, 0, 0, 0); stage(0, 1, 0, 0); stage(1, 0, 0, 0); stage(1, 1, 0, 0);
  if (NTt > 1) {
    stage(0, 0, 1, 1); stage(0, 1, 1, 1); stage(1, 0, 1, 1);
    asm volatile("s_waitcnt vmcnt(6)" ::: "memory");
  } else {
    asm volatile("s_waitcnt vmcnt(0)" ::: "memory");
  }
  BAR();

#define TILE(U, BU) do {                                                       \
    const int u_ = (U);                                                        \
    /* ---- p1: A[m0-3], B[n0-1]; stage B1(u+1) ---- */                        \
    _Pragma("unroll")                                                          \
    for (int mi = 0; mi < 4; ++mi) {                                           \
      afr[mi][0] = ldA(BU, mi, 0); afr[mi][1] = ldA(BU, mi, 1);                \
    }                                                                          \
    _Pragma("unroll")                                                          \
    for (int nj = 0; nj < 2; ++nj) {                                           \
      bfr[nj][0] = ldB(BU, nj, 0); bfr[nj][1] = ldB(BU, nj, 1);                \
    }                                                                          \
    if (u_ + 1 < NTt) stage(1, 1, 1 - (BU), u_ + 1);                           \
    __builtin_amdgcn_s_setprio(1);                                             \
    _Pragma("unroll")                                                          \
    for (int mi = 0; mi < 4; ++mi)                                             \
      _Pragma("unroll")                                                        \
      for (int nj = 0; nj < 2; ++nj) {                                         \
        acc[mi][nj] = __builtin_amdgcn_mfma_f32_16x16x32_bf16(                 \
            afr[mi][0], bfr[nj][0], acc[mi][nj], 0, 0, 0);                     \
        acc[mi][nj] = __builtin_amdgcn_mfma_f32_16x16x32_bf16(                 \
            afr[mi][1], bfr[nj][1], acc[mi][nj], 0, 0, 0);                     \
      }                                                                        \
    __builtin_amdgcn_s_setprio(0);                                             \
    BAR();                                                                     \
    /* ---- p2: A[m4-7] (A regions retire) ---- */                             \
    _Pragma("unroll")                                                          \
    for (int mi = 4; mi < 8; ++mi) {                                           \
      afr[mi][0] = ldA(BU, mi, 0); afr[mi][1] = ldA(BU, mi, 1);                \
    }                                                                          \
    __builtin_amdgcn_s_setprio(1);                                             \
    _Pragma("unroll")                                                          \
    for (int mi = 4; mi < 8; ++mi)                                             \
      _Pragma("unroll")                                                        \
      for (int nj = 0; nj < 2; ++nj) {                                         \
        acc[mi][nj] = __builtin_amdgcn_mfma_f32_16x16x32_bf16(                 \
            afr[mi][0], bfr[nj][0], acc[mi][nj], 0, 0, 0);                     \
        acc[mi][nj] = __builtin_amdgcn_mfma_f32_16x16x32_bf16(                 \
            afr[mi][1], bfr[nj][1], acc[mi][nj], 0, 0, 0);                     \
      }                                                                        \
    __builtin_amdgcn_s_setprio(0);                                             \
    BAR();                                                                     \
    /* ---- p3: B[n2-3]; stage A0(u+2) (A dead) ---- */                        \
    _Pragma("unroll")                                                          \
    for (int nj = 0; nj < 2; ++nj) {                                           \
      bfr[nj][0] = ldB(BU, 2 + nj, 0); bfr[nj][1] = ldB(BU, 2 + nj, 1);        \
    }                                                                          \
    if (u_ + 2 < NTt) stage(0, 0, BU, u_ + 2);                                 \
    __builtin_amdgcn_s_setprio(1);                                             \
    _Pragma("unroll")                                                          \
    for (int mi = 0; mi < 4; ++mi)                                             \
      _Pragma("unroll")                                                        \
      for (int nj = 0; nj < 2; ++nj) {                                         \
        acc[mi][2 + nj] = __builtin_amdgcn_mfma_f32_16x16x32_bf16(             \
            afr[mi][0], bfr[nj][0], acc[mi][2 + nj], 0, 0, 0);                 \
        acc[mi][2 + nj] = __builtin_amdgcn_mfma_f32_16x16x32_bf16(             \
            afr[mi][1], bfr[nj][1], acc[mi][2 + nj], 0, 0, 0);                 \
      }                                                                        \
    __builtin_amdgcn_s_setprio(0);                                             \
    BAR();                                                                     \
    /* ---- p4: stage A1,B0(u+2) (B dead); counted vmcnt ---- */               \
    if (u_ + 2 < NTt) { stage(0, 1, BU, u_ + 2); stage(1, 0, BU, u_ + 2); }    \
    __builtin_amdgcn_s_setprio(1);                                             \
    _Pragma("unroll")                                                          \
    for (int mi = 4; mi < 8; ++mi)                                             \
      _Pragma("unroll")                                                        \
      for (int nj = 0; nj < 2; ++nj) {                                         \
        acc[mi][2 + nj] = __builtin_amdgcn_mfma_f32_16x16x32_bf16(             \
            afr[mi][0], bfr[nj][0], acc[mi][2 + nj], 0, 0, 0);                 \
        acc[mi][2 + nj] = __builtin_amdgcn_mfma_f32_16x16x32_bf16(             \
            afr[mi][1], bfr[nj][1], acc[mi][2 + nj], 0, 0, 0);                 \
      }                                                                        \
    __builtin_amdgcn_s_setprio(0);                                             \
    if (u_ + 2 < NTt) asm volatile("s_waitcnt vmcnt(6)" ::: "memory");         \
    else              asm volatile("s_waitcnt vmcnt(0)" ::: "memory");         \
    BAR();                                                                     \
  } while (0)

  for (int u = 0; u < NTt; u += 2) {
    TILE(u, 0);
    TILE(u + 1, 1);
  }
#undef TILE

  // ---- LDS-coalesced epilogue: (x+bias)*0.1, full-line NON-TEMPORAL stores ----
  float* scratch = (float*)&lds[0][0][0][0];   // 32768 f32 = 128 x 256
  #pragma unroll
  for (int p = 0; p < 2; ++p) {
    if (wr == p) {
      #pragma unroll
      for (int ni = 0; ni < 4; ++ni) {
        const int col = (wc << 6) + ni * 16 + r;
        const float bv = bias[n0 + col];
        #pragma unroll
        for (int mi = 0; mi < 8; ++mi) {
          #pragma unroll
          for (int e = 0; e < 4; ++e) {
            const int row = mi * 16 + (q << 2) + e;
            const int cs  = col ^ (((row >> 2) & 1) << 4);
            scratch[row * 256 + cs] = (acc[mi][ni][e] + bv) * 0.1f;
          }
        }
      }
    }
    __syncthreads();
    #pragma unroll
    for (int rowi = 0; rowi < 16; ++rowi) {
      const int row = (wave << 4) + rowi;
      const int cb  = (lane << 2) ^ (((row >> 2) & 1) << 4);
      const f32x4 v4 = *(const f32x4*)&scratch[row * 256 + cb];
      __builtin_nontemporal_store(
          v4, (f32x4*)&out[(size_t)(m0 + (p << 7) + row) * ldOut + n0 + (lane << 2)]);
    }
    __syncthreads();
  }
}

// ---------------- LayerNorm over last dim (1024), f32 in -> bf16 out ----------------
__global__ void ln_kernel(const float* __restrict__ merged,
                          const float* __restrict__ lnw,
                          const float* __restrict__ lnb,
                          unsigned short* __restrict__ normed) {
  const int row = blockIdx.x;
  const float4 v = ((const float4*)(merged + (size_t)row * HIDDEN))[threadIdx.x];
  float s  = v.x + v.y + v.z + v.w;
  float ss = v.x * v.x + v.y * v.y + v.z * v.z + v.w * v.w;
  #pragma unroll
  for (int off = 32; off > 0; off >>= 1) {
    s  += __shfl_down(s, off, 64);
    ss += __shfl_down(ss, off, 64);
  }
  __shared__ float red[8];
  const int wvi = threadIdx.x >> 6;
  if ((threadIdx.x & 63) == 0) { red[wvi] = s; red[4 + wvi] = ss; }
  __syncthreads();
  s  = red[0] + red[1] + red[2] + red[3];
  ss = red[4] + red[5] + red[6] + red[7];
  const float mu  = s * (1.0f / HIDDEN);
  const float var = ss * (1.0f / HIDDEN) - mu * mu;
  const float rs  = rsqrtf(var + 1e-5f);
  const float4 w4 = ((const float4*)lnw)[threadIdx.x];
  const float4 b4 = ((const float4*)lnb)[threadIdx.x];
  ushort4 o;
  o.x = f2b((v.x - mu) * rs * w4.x + b4.x);
  o.y = f2b((v.y - mu) * rs * w4.y + b4.y);
  o.z = f2b((v.z - mu) * rs * w4.z + b4.z);
  o.w = f2b((v.w - mu) * rs * w4.w + b4.w);
  ((ushort4*)(normed + (size_t)row * HIDDEN))[threadIdx.x] = o;
}

extern "C" void kernel_launch(void* const* d_in, const int* in_sizes, int n_in,
                              void* d_out, int out_size, void* d_ws, size_t ws_size,
                              hipStream_t stream) {
  const int*   tokens = (const int*)d_in[0];
  const float* E      = (const float*)d_in[1];
  const float* Wc     = (const float*)d_in[2];
  const float* bc     = (const float*)d_in[3];
  const float* Wh     = (const float*)d_in[4];
  const float* bh     = (const float*)d_in[5];
  const float* Wm     = (const float*)d_in[6];
  const float* bm     = (const float*)d_in[7];
  const float* Wo     = (const float*)d_in[8];
  const float* bo     = (const float*)d_in[9];
  const float* lnw    = (const float*)d_in[10];
  const float* lnb    = (const float*)d_in[11];

  char* p = (char*)d_ws;
  unsigned short* WcT  = (unsigned short*)p; p += (size_t)HIDDEN * EMBED * 2;
  unsigned short* WhT  = (unsigned short*)p; p += (size_t)HIDDEN * EMBED * 2;
  unsigned short* WmT  = (unsigned short*)p; p += (size_t)HIDDEN * (2 * HIDDEN) * 2;
  unsigned short* WoT  = (unsigned short*)p; p += (size_t)VOCAB * HIDDEN * 2;
  unsigned short* emb  = (unsigned short*)p; p += (size_t)NROWS * EMBED * 2;
  unsigned short* hist = (unsigned short*)p; p += (size_t)NROWS * EMBED * 2;
  unsigned short* cat  = (unsigned short*)p; p += (size_t)NROWS * (2 * HIDDEN) * 2;
  float*          mrg  = (float*)p;          p += (size_t)NROWS * HIDDEN * 4;
  unsigned short* nrm  = (unsigned short*)p; p += (size_t)NROWS * HIDDEN * 2;
  float*          csum = (float*)p;          p += (size_t)BATCH * NCHUNK * EMBED * 4;
  if ((size_t)(p - (char*)d_ws) > ws_size)
    fprintf(stderr, "WS TOO SMALL: need %zu have %zu\n", (size_t)(p - (char*)d_ws), ws_size);

  // fused prep: 8768 transpose tiles + 256 gather blocks, one launch
  prep_kernel<<<8768 + 256, 512, 0, stream>>>(
      tokens, E, emb, csum, Wc, Wh, Wm, Wo, WcT, WhT, WmT, WoT);
  scan_excl_kernel<<<dim3(BATCH, EMBED / 128), 128, 0, stream>>>(csum);
  scan_emit_kernel<<<BATCH * NCHUNK, EMBED, 0, stream>>>(emb, csum, hist);

  const int nwgEnc = (NROWS / BM) * (HIDDEN / BN);   // 256 tiles per slice

  // cur_enc / hist_enc fused into one launch (z=2) -> concatenated [4096, 2048] bf16
  gemm_bt_kernel<0><<<dim3(nwgEnc, 1, 2), 256, 0, stream>>>(
      emb, WcT, bc, cat, NROWS, HIDDEN, EMBED, 2 * HIDDEN, 0,
      hist, WhT, bh, HIDDEN);
  // merged = relu(cat @ Wm + bm), kept f32 for LN accuracy
  gemm_bt_kernel<1><<<dim3(nwgEnc, 1, 1), 256, 0, stream>>>(
      cat, WmT, bm, mrg, NROWS, HIDDEN, 2 * HIDDEN, HIDDEN, 0,
      nullptr, nullptr, nullptr, 0);
  ln_kernel<<<NROWS, 256, 0, stream>>>(mrg, lnw, lnb, nrm);

  // logits = (normed @ Wo + bo) * 0.1 -> d_out f32, 256^2 deep-pipelined kernel
  const int nwgOut = (NROWS / 256) * (VOCAB / 256);  // 16 * 125 = 2000
  gemm256_out_kernel<<<dim3(nwgOut), 512, 0, stream>>>(
      nrm, WoT, bo, (float*)d_out, NROWS, VOCAB, HIDDEN, VOCAB);
}